// Round 21
// baseline (283.381 us; speedup 1.0000x reference)
//
#include <hip/hip_runtime.h>
#include <math.h>

#define BSZ 256
#define DIM 128
#define NHD 4
#define NPATCH 196
#define NACT 15

typedef float f32x4 __attribute__((ext_vector_type(4)));
typedef __bf16 bf16x8 __attribute__((ext_vector_type(8)));
typedef short short8 __attribute__((ext_vector_type(8)));

__device__ __forceinline__ float wred_sum(float v) {
#pragma unroll
    for (int m = 1; m < 64; m <<= 1) v += __shfl_xor(v, m, 64);
    return v;
}
__device__ __forceinline__ float wred_max(float v) {
#pragma unroll
    for (int m = 1; m < 64; m <<= 1) v = fmaxf(v, __shfl_xor(v, m, 64));
    return v;
}
__device__ __forceinline__ ushort f2bf(float f) {  // RNE bf16
    unsigned u = __float_as_uint(f);
    return (ushort)((u + 0x7fffu + ((u >> 16) & 1u)) >> 16);
}

// ---------------------------------------------------------------------------
// Weight convert+transpose to bf16 [N][K] (patch K-permuted), packed.
// ---------------------------------------------------------------------------
__global__ __launch_bounds__(256) void k_wconv(
    const float* __restrict__ pW, const float* __restrict__ qkvW,
    const float* __restrict__ outW, const float* __restrict__ ff1W,
    const float* __restrict__ ff2W, const float* __restrict__ ckvW,
    ushort* __restrict__ o)
{
    int i = blockIdx.x * 256 + threadIdx.x;
    if (i < 98304) {
        int n = i / 768, kp = i % 768;
        int c = kp >> 8, q = kp & 255;
        o[i] = f2bf(pW[(q * 3 + c) * 128 + n]); return;
    }
    i -= 98304;
    if (i < 49152) { int n = i >> 7, k = i & 127; o[98304 + i] = f2bf(qkvW[k * 384 + n]); return; }
    i -= 49152;
    if (i < 16384) { int n = i >> 7, k = i & 127; o[147456 + i] = f2bf(outW[k * 128 + n]); return; }
    i -= 16384;
    if (i < 8192)  { int n = i >> 7, k = i & 127; o[163840 + i] = f2bf(ff1W[k * 64 + n]); return; }
    i -= 8192;
    if (i < 8192)  { int n = i >> 6, k = i & 63;  o[172032 + i] = f2bf(ff2W[k * 128 + n]); return; }
    i -= 8192;
    if (i < 32768) { int n = i >> 7, k = i & 127; o[180224 + i] = f2bf(ckvW[k * 384 + 128 + n]); return; }
}

// ---------------------------------------------------------------------------
// MERGED kernel (verified r18/r19): blocks [0,256) = dec1 (L2 prefetch);
// blocks [256,1040) = patchify-GEMM + fused encoder-QKV stage.
// ---------------------------------------------------------------------------
__global__ __launch_bounds__(512) void k_pg_dec1(
    const float* __restrict__ img, const ushort* __restrict__ Wt,
    const float* __restrict__ pbias, const float* __restrict__ pe,
    float* __restrict__ C,
    const ushort* __restrict__ qkvWt, const float* __restrict__ qkvB,
    ushort* __restrict__ QKVb,
    const float* __restrict__ sk,
    const float* __restrict__ W1, const float* __restrict__ b1,
    const float* __restrict__ W2, const float* __restrict__ b2,
    const float* __restrict__ W3, const float* __restrict__ b3,
    const float* __restrict__ ang, const float* __restrict__ px,
    const float* __restrict__ py,
    const float* __restrict__ actW, const float* __restrict__ actb,
    const float* __restrict__ saW, const float* __restrict__ sab,
    const float* __restrict__ saoW, const float* __restrict__ saob,
    const float* __restrict__ ln1s, const float* __restrict__ ln1b,
    const float* __restrict__ caW, const float* __restrict__ cab,
    float* __restrict__ TGo, float* __restrict__ DQ)
{
    extern __shared__ char smem[];
    const int t = threadIdx.x;
    const int w = t >> 6, l = t & 63;

    if (blockIdx.x >= 256) {
        ushort* As = (ushort*)smem;          // 16 KB (2 x 64x64)
        ushort* Ws = As + 2 * 64 * 64;       // 32 KB (2 x 128x64)
        const bool act = t < 256;
        const int pb = blockIdx.x - 256;
        const int p = pb >> 2, bq = pb & 3;
        const int hp_ = p / 14, wp = p % 14;
        const int r0 = p * 256 + bq * 64;
        const int wm = w >> 1, wn = w & 1;
        const int lrow = l & 15, lk = l >> 4;
        const int arow = (t & 255) >> 2;
        const int b_img = bq * 64 + arow;
        const float* gimg = img + (size_t)b_img * 150528 + hp_ * 3584 + wp * 16;

        f32x4 acc[2][4];
#pragma unroll
        for (int m = 0; m < 2; ++m)
#pragma unroll
            for (int n = 0; n < 4; ++n) acc[m][n] = (f32x4)0.f;

        float4 va[4];
        short8 wr[4];

        auto loadT = [&](int kc) {
            if (!act) return;
            const int c = kc >> 8, p1q = (kc >> 6) & 3;
            const float* gc = gimg + c * 50176 + p1q * 896;
#pragma unroll
            for (int i = 0; i < 4; ++i)
                va[i] = *(const float4*)(gc + i * 224 + (t & 3) * 4);
#pragma unroll
            for (int j = 0; j < 4; ++j) {
                const int i2 = t + 256 * j;
                const int row = i2 >> 3, ch = i2 & 7;
                wr[j] = *(const short8*)(Wt + (size_t)row * 768 + kc + ch * 8);
            }
        };
        auto storeT = [&](int buf) {
            if (!act) return;
            ushort* Ab = As + buf * 64 * 64;
            ushort* Wb = Ws + buf * 128 * 64;
#pragma unroll
            for (int i = 0; i < 4; ++i) {
                ushort4 o4;
                o4.x = f2bf(va[i].x); o4.y = f2bf(va[i].y);
                o4.z = f2bf(va[i].z); o4.w = f2bf(va[i].w);
                const int kq = (t & 3) + 4 * i;
                const int bo = (kq * 8) ^ ((arow & 7) << 4);
                *(ushort4*)((char*)Ab + arow * 128 + bo) = o4;
            }
#pragma unroll
            for (int j = 0; j < 4; ++j) {
                const int i2 = t + 256 * j;
                const int row = i2 >> 3, ch = i2 & 7;
                const int sw = (ch * 16) ^ ((row & 7) << 4);
                *(short8*)((char*)Wb + row * 128 + sw) = wr[j];
            }
        };
        auto mfmaT = [&](int buf) {
            if (!act) return;
            const ushort* Ab = As + buf * 64 * 64;
            const ushort* Wb = Ws + buf * 128 * 64;
#pragma unroll
            for (int ks = 0; ks < 2; ++ks) {
                bf16x8 af[2], bfr[4];
#pragma unroll
                for (int m = 0; m < 2; ++m) {
                    const int row = wm * 32 + m * 16 + lrow;
                    const int col = (ks * 64 + lk * 16) ^ ((row & 7) << 4);
                    af[m] = *(const bf16x8*)((const char*)Ab + row * 128 + col);
                }
#pragma unroll
                for (int n = 0; n < 4; ++n) {
                    const int row = wn * 64 + n * 16 + lrow;
                    const int col = (ks * 64 + lk * 16) ^ ((row & 7) << 4);
                    bfr[n] = *(const bf16x8*)((const char*)Wb + row * 128 + col);
                }
#pragma unroll
                for (int m = 0; m < 2; ++m)
#pragma unroll
                    for (int n = 0; n < 4; ++n)
                        acc[m][n] = __builtin_amdgcn_mfma_f32_16x16x32_bf16(
                            af[m], bfr[n], acc[m][n], 0, 0, 0);
            }
        };

        loadT(0);
        for (int it = 0; it < 12; it += 2) {
            storeT(0);
            if (it + 1 < 12) loadT((it + 1) * 64);
            __syncthreads();
            mfmaT(0);
            storeT(1);
            if (it + 2 < 12) loadT((it + 2) * 64);
            __syncthreads();
            mfmaT(1);
        }

        __syncthreads();
        const int crow0 = (l >> 4) * 4;
        const int ccol = l & 15;
        if (act) {
#pragma unroll
            for (int m = 0; m < 2; ++m) {
                const int rowb = wm * 32 + m * 16 + crow0;
#pragma unroll
                for (int n = 0; n < 4; ++n) {
                    const int col = wn * 64 + n * 16 + ccol;
                    const float bv = pbias[col] + pe[p * 128 + col];
#pragma unroll
                    for (int j = 0; j < 4; ++j) {
                        const int row = rowb + j;
                        const float v = acc[m][n][j] + bv;
                        C[(size_t)(r0 + row) * 128 + col] = v;
                        const int bo = row * 256 + (((col >> 3) * 16) ^ ((row & 7) << 4)) + (col & 7) * 2;
                        *(ushort*)((char*)As + bo) = f2bf(v);
                    }
                }
            }
        }

        // ---- fused QKV stage (verified r18) ----
        const int wm2 = w >> 1;
        const int wn2 = w & 1;
        for (int cc = 0; cc < 3; ++cc) {
            __syncthreads();
            for (int i = t; i < 2048; i += 512) {
                const int row = i >> 4, ch = i & 15;
                *(short8*)((char*)Ws + row * 256 + ((ch * 16) ^ ((row & 7) << 4))) =
                    *(const short8*)(qkvWt + (size_t)(cc * 128 + row) * 128 + ch * 8);
            }
            __syncthreads();
            f32x4 a2[4];
#pragma unroll
            for (int n = 0; n < 4; ++n) a2[n] = (f32x4)0.f;
#pragma unroll
            for (int ks = 0; ks < 4; ++ks) {
                const int arow2 = wm2 * 16 + lrow;
                const int acol = (ks * 64 + lk * 16) ^ ((arow2 & 7) << 4);
                const bf16x8 af = *(const bf16x8*)((const char*)As + arow2 * 256 + acol);
#pragma unroll
                for (int n = 0; n < 4; ++n) {
                    const int brow = wn2 * 64 + n * 16 + lrow;
                    const int bcol = (ks * 64 + lk * 16) ^ ((brow & 7) << 4);
                    const bf16x8 bf = *(const bf16x8*)((const char*)Ws + brow * 256 + bcol);
                    a2[n] = __builtin_amdgcn_mfma_f32_16x16x32_bf16(af, bf, a2[n], 0, 0, 0);
                }
            }
#pragma unroll
            for (int n = 0; n < 4; ++n) {
                const int gcol = cc * 128 + wn2 * 64 + n * 16 + ccol;
                const float bb = qkvB[gcol];
#pragma unroll
                for (int j = 0; j < 4; ++j) {
                    const int grow = r0 + wm2 * 16 + crow0 + j;
                    QKVb[(size_t)grow * 384 + gcol] = f2bf(a2[n][j] + bb);
                }
            }
        }
        return;
    }

    // ================= dec1 body (r17-verbatim, incl. L2 prefetch) ==========
    float* tg  = (float*)smem;
    float* qkv = tg + 1920;
    float* ao  = qkv + 5820;
    float* xr  = ao + 1920;
    float* h1  = xr + 256;
    float* h2  = h1 + 256;
    float* s3  = h2 + 256;
    float* pbv = s3 + 100;
    float* hp  = pbv + 64;
    const int b = blockIdx.x;

    {
        float pf = 0.f;
#define PFW(P, N) for (int i = t * 32; i < (N); i += 512 * 32) pf += P[i];
        PFW(W1, 200 * 256)
        PFW(W2, 256 * 256)
        PFW(W3, 256 * 100)
        PFW(actW, 118 * 128)
        PFW(saW, 128 * 384)
        PFW(saoW, 128 * 128)
        PFW(caW, 128 * 384)
#undef PFW
        asm volatile("" :: "v"(pf));
    }

    if (t < 256) xr[t] = (t < 200) ? sk[(size_t)b * 200 + t] : 0.f;
    __syncthreads();
    {
        const int c = t & 255, g = t >> 8;
        const int k0 = g * 100;
        float a = 0.f;
#pragma unroll 10
        for (int k = k0; k < k0 + 100; ++k) a += xr[k] * W1[k * 256 + c];
        hp[g * 256 + c] = a;
    }
    __syncthreads();
    if (t < 256) h1[t] = fmaxf(hp[t] + hp[256 + t] + b1[t], 0.f);
    __syncthreads();
    {
        const int c = t & 255, g = t >> 8;
        const int k0 = g * 128;
        float a = 0.f;
#pragma unroll 8
        for (int k = k0; k < k0 + 128; ++k) a += h1[k] * W2[k * 256 + c];
        hp[g * 256 + c] = a;
    }
    __syncthreads();
    if (t < 256) h2[t] = fmaxf(hp[t] + hp[256 + t] + b2[t], 0.f);
    __syncthreads();
    if (t < 400) {
        const int c = t % 100, g = t / 100;
        const int k0 = g * 64;
        float a = 0.f;
#pragma unroll 8
        for (int k = k0; k < k0 + 64; ++k) a += h2[k] * W3[k * 100 + c];
        hp[g * 256 + c] = a;
    }
    __syncthreads();
    if (t < 100) s3[t] = hp[t] + hp[256 + t] + hp[512 + t] + hp[768 + t] + b3[t];
    __syncthreads();
    {
        const int c = t & 127, g = t >> 7;
        const int k0 = g * 25;
        float a = 0.f;
#pragma unroll 5
        for (int k = k0; k < k0 + 25; ++k) a += s3[k] * actW[(18 + k) * 128 + c];
        hp[g * 256 + c] = a;
    }
    __syncthreads();
    if (t < 128) {
        const float base = actb[t] + hp[t] + hp[256 + t] + hp[512 + t] + hp[768 + t] +
                           ang[b] * actW[15 * 128 + t] + px[b] * actW[16 * 128 + t] +
                           py[b] * actW[17 * 128 + t];
#pragma unroll
        for (int i = 0; i < 15; ++i) tg[i * 128 + t] = base + actW[i * 128 + t];
    }
    __syncthreads();

    if (t < 384) {
        float acc[15];
#pragma unroll
        for (int r = 0; r < 15; ++r) acc[r] = 0.f;
#pragma unroll 4
        for (int k = 0; k < 128; ++k) {
            const float wv = saW[(size_t)k * 384 + t];
#pragma unroll
            for (int r = 0; r < 15; ++r) acc[r] += tg[r * 128 + k] * wv;
        }
        const float bb = sab[t];
#pragma unroll
        for (int r = 0; r < 15; ++r) qkv[r * 388 + t] = acc[r] + bb;
    }
    __syncthreads();

    const float rs = 0.17677669529663687f;
    if (w < 4) {
        for (int qi = 0; qi < 15; ++qi) {
            float s = -3.0e38f;
            if (l < 15) {
                s = 0.f;
#pragma unroll
                for (int d = 0; d < 32; ++d)
                    s += qkv[qi * 388 + w * 32 + d] * qkv[l * 388 + 128 + w * 32 + d];
                s *= rs;
            }
            const float m = wred_max(s);
            const float pv = (l < 15) ? __expf(s - m) : 0.f;
            const float sum = wred_sum(pv);
            if (l < 15) pbv[w * 16 + l] = pv;
            if (l < 32) {
                float o = 0.f;
#pragma unroll
                for (int j = 0; j < 15; ++j) o += pbv[w * 16 + j] * qkv[j * 388 + 256 + w * 32 + l];
                ao[qi * 128 + w * 32 + l] = o / sum;
            }
        }
    }
    __syncthreads();

    {
        const int c = t & 127, g = t >> 7;
        const int r3 = (g + 12 < 15) ? g + 12 : 0;
        float a0 = 0.f, a1 = 0.f, a2 = 0.f, a3 = 0.f;
#pragma unroll 4
        for (int k = 0; k < 128; ++k) {
            const float wv = saoW[(size_t)k * 128 + c];
            a0 += ao[g * 128 + k] * wv;
            a1 += ao[(g + 4) * 128 + k] * wv;
            a2 += ao[(g + 8) * 128 + k] * wv;
            a3 += ao[r3 * 128 + k] * wv;
        }
        const float bb = saob[c];
        qkv[g * 388 + c]       = a0 + bb + tg[g * 128 + c];
        qkv[(g + 4) * 388 + c] = a1 + bb + tg[(g + 4) * 128 + c];
        qkv[(g + 8) * 388 + c] = a2 + bb + tg[(g + 8) * 128 + c];
        if (g + 12 < 15) qkv[(g + 12) * 388 + c] = a3 + bb + tg[(g + 12) * 128 + c];
    }
    __syncthreads();
    for (int r = w; r < 15; r += 8) {
        const float x0 = qkv[r * 388 + l], x1 = qkv[r * 388 + l + 64];
        const float sm = wred_sum(x0 + x1);
        const float sq = wred_sum(x0 * x0 + x1 * x1);
        const float mean = sm * 0.0078125f;
        const float rstd = rsqrtf(sq * 0.0078125f - mean * mean + 1e-5f);
        const float y0 = (x0 - mean) * rstd * ln1s[l] + ln1b[l];
        const float y1 = (x1 - mean) * rstd * ln1s[l + 64] + ln1b[l + 64];
        tg[r * 128 + l] = y0; tg[r * 128 + l + 64] = y1;
        float* g2 = TGo + ((size_t)r * 256 + b) * 128;
        g2[l] = y0; g2[l + 64] = y1;
    }
    __syncthreads();

    {
        const int c = t & 127, g = t >> 7;
        const int r3 = (g + 12 < 15) ? g + 12 : 0;
        float a0 = 0.f, a1 = 0.f, a2 = 0.f, a3 = 0.f;
#pragma unroll 4
        for (int k = 0; k < 128; ++k) {
            const float wv = caW[(size_t)k * 384 + c];
            a0 += tg[g * 128 + k] * wv;
            a1 += tg[(g + 4) * 128 + k] * wv;
            a2 += tg[(g + 8) * 128 + k] * wv;
            a3 += tg[r3 * 128 + k] * wv;
        }
        const float bb = cab[c];
        DQ[((size_t)g * 256 + b) * 128 + c]       = a0 + bb;
        DQ[((size_t)(g + 4) * 256 + b) * 128 + c] = a1 + bb;
        DQ[((size_t)(g + 8) * 256 + b) * 128 + c] = a2 + bb;
        if (g + 12 < 15) DQ[((size_t)(g + 12) * 256 + b) * 128 + c] = a3 + bb;
    }
}

// ---------------------------------------------------------------------------
// bf16 MFMA GEMM 64x128 + residual + LayerNorm fused epilogue (verified r5);
// fused FF1 / cross-KV stages now stage their B-operand in 32-col chunks
// (8 KB) overlaid into the dead As region: LDS 41 -> 25.6 KB, 3 -> 6
// blocks/CU, 784-block grid fits one scheduling wave. Math bit-identical.
// ---------------------------------------------------------------------------
template <int FF, int CKV>
__global__ __launch_bounds__(256) void k_gemm_ln(
    const ushort* __restrict__ A, int lda,
    const ushort* __restrict__ Wt, int K,
    const float* __restrict__ bias,
    const float* __restrict__ resid,
    const float* __restrict__ lns, const float* __restrict__ lnbi,
    float* __restrict__ Co, ushort* __restrict__ Cb,
    const ushort* __restrict__ ffW, const float* __restrict__ ffb,
    ushort* __restrict__ Fb,
    const ushort* __restrict__ ckvW, const float* __restrict__ ckvB,
    float* __restrict__ KVout)
{
    __shared__ ushort As[64 * 64];           // K-loop A tiles; later B-chunk buf
    __shared__ ushort Ws[128 * 64];          // K-loop W tiles; later y[64][256B]
    __shared__ float psum[64][2][2];
    const int t = threadIdx.x;
    const int w = t >> 6, l = t & 63;
    const int r0 = blockIdx.x * 64;
    const int wm = w >> 1, wn = w & 1;
    const int lrow = l & 15, lk = l >> 4;

    f32x4 acc[2][4];
#pragma unroll
    for (int m = 0; m < 2; ++m)
#pragma unroll
        for (int n = 0; n < 4; ++n) acc[m][n] = (f32x4)0.f;

    for (int kc = 0; kc < K; kc += 64) {
        __syncthreads();
#pragma unroll
        for (int i = t; i < 64 * 8; i += 256) {
            const int row = i >> 3, ch = i & 7;
            const int sw = (ch * 16) ^ ((row & 7) << 4);
            *(short8*)((char*)As + row * 128 + sw) =
                *(const short8*)(A + (size_t)(r0 + row) * lda + kc + ch * 8);
        }
#pragma unroll
        for (int i = t; i < 128 * 8; i += 256) {
            const int row = i >> 3, ch = i & 7;
            const int sw = (ch * 16) ^ ((row & 7) << 4);
            *(short8*)((char*)Ws + row * 128 + sw) =
                *(const short8*)(Wt + (size_t)row * K + kc + ch * 8);
        }
        __syncthreads();
#pragma unroll
        for (int ks = 0; ks < 2; ++ks) {
            bf16x8 af[2], bfr[4];
#pragma unroll
            for (int m = 0; m < 2; ++m) {
                const int row = wm * 32 + m * 16 + lrow;
                const int col = (ks * 64 + lk * 16) ^ ((row & 7) << 4);
                af[m] = *(const bf16x8*)((const char*)As + row * 128 + col);
            }
#pragma unroll
            for (int n = 0; n < 4; ++n) {
                const int row = wn * 64 + n * 16 + lrow;
                const int col = (ks * 64 + lk * 16) ^ ((row & 7) << 4);
                bfr[n] = *(const bf16x8*)((const char*)Ws + row * 128 + col);
            }
#pragma unroll
            for (int m = 0; m < 2; ++m)
#pragma unroll
                for (int n = 0; n < 4; ++n)
                    acc[m][n] = __builtin_amdgcn_mfma_f32_16x16x32_bf16(
                        af[m], bfr[n], acc[m][n], 0, 0, 0);
        }
    }

    const int crow0 = (l >> 4) * 4;
    const int ccol = l & 15;
#pragma unroll
    for (int m = 0; m < 2; ++m) {
        const int growb = r0 + wm * 32 + m * 16 + crow0;
#pragma unroll
        for (int n = 0; n < 4; ++n) {
            const int gcol = wn * 64 + n * 16 + ccol;
            const float bv = bias[gcol];
#pragma unroll
            for (int j = 0; j < 4; ++j) {
                float v = acc[m][n][j] + bv;
                if (resid) v += resid[(size_t)(growb + j) * 128 + gcol];
                acc[m][n][j] = v;
            }
        }
    }
#pragma unroll
    for (int m = 0; m < 2; ++m)
#pragma unroll
        for (int j = 0; j < 4; ++j) {
            float s_ = 0.f, q_ = 0.f;
#pragma unroll
            for (int n = 0; n < 4; ++n) {
                const float x = acc[m][n][j];
                s_ += x; q_ += x * x;
            }
#pragma unroll
            for (int mk = 1; mk < 16; mk <<= 1) {
                s_ += __shfl_xor(s_, mk, 64);
                q_ += __shfl_xor(q_, mk, 64);
            }
            if (ccol == 0) {
                const int r = wm * 32 + m * 16 + crow0 + j;
                psum[r][wn][0] = s_;
                psum[r][wn][1] = q_;
            }
        }
    __syncthreads();   // psum ready; ALL K-loop reads of As & Ws complete
    float mean_[2][4], rstd_[2][4];
#pragma unroll
    for (int m = 0; m < 2; ++m)
#pragma unroll
        for (int j = 0; j < 4; ++j) {
            const int r = wm * 32 + m * 16 + crow0 + j;
            const float sum = psum[r][0][0] + psum[r][1][0];
            const float sq  = psum[r][0][1] + psum[r][1][1];
            const float mean = sum * 0.0078125f;
            const float var = sq * 0.0078125f - mean * mean;
            mean_[m][j] = mean;
            rstd_[m][j] = rsqrtf(var + 1e-5f);
        }
#pragma unroll
    for (int m = 0; m < 2; ++m) {
        const int growb = r0 + wm * 32 + m * 16 + crow0;
#pragma unroll
        for (int n = 0; n < 4; ++n) {
            const int gcol = wn * 64 + n * 16 + ccol;
            const float sv = lns[gcol], bv2 = lnbi[gcol];
#pragma unroll
            for (int j = 0; j < 4; ++j) {
                const float y = (acc[m][n][j] - mean_[m][j]) * rstd_[m][j] * sv + bv2;
                acc[m][n][j] = y;
                const size_t oi = (size_t)(growb + j) * 128 + gcol;
                if (Co) Co[oi] = y;
                if (Cb) Cb[oi] = f2bf(y);
            }
        }
    }

    if constexpr (FF || CKV) {
        // Restage y (bf16) into Ws reinterpreted as [64 rows][256 B], swizzled.
#pragma unroll
        for (int m = 0; m < 2; ++m) {
            const int rowb = wm * 32 + m * 16 + crow0;
#pragma unroll
            for (int n = 0; n < 4; ++n) {
                const int c = wn * 64 + n * 16 + ccol;
                const int cb = ((c >> 3) * 16);
#pragma unroll
                for (int j = 0; j < 4; ++j) {
                    const int row = rowb + j;
                    const int bo = row * 256 + ((cb) ^ ((row & 7) << 4)) + (c & 7) * 2;
                    *(ushort*)((char*)Ws + bo) = f2bf(acc[m][n][j]);
                }
            }
        }
    }
    ushort* Bc = As;   // 8 KB chunk buffer overlaid on dead A-tile region

    if constexpr (FF) {
        // out[64][64] = y @ ffW^T in 2 chunks of 32 cols; K=128 each.
        for (int cc = 0; cc < 2; ++cc) {
            __syncthreads();   // As K-loop reads done (cc=0) / prev chunk done
            for (int i = t; i < 512; i += 256) {
                const int row = i >> 4, ch = i & 15;
                *(short8*)((char*)Bc + row * 256 + ((ch * 16) ^ ((row & 7) << 4))) =
                    *(const short8*)(ffW + (size_t)(cc * 32 + row) * 128 + ch * 8);
            }
            __syncthreads();   // y + Bc visible
            f32x4 accF[2];
#pragma unroll
            for (int n = 0; n < 2; ++n) accF[n] = (f32x4)0.f;
#pragma unroll
            for (int ks = 0; ks < 4; ++ks) {
                const int arow2 = w * 16 + lrow;
                const int acol = (ks * 64 + lk * 16) ^ ((arow2 & 7) << 4);
                const bf16x8 af = *(const bf16x8*)((const char*)Ws + arow2 * 256 + acol);
#pragma unroll
                for (int n = 0; n < 2; ++n) {
                    const int brow = n * 16 + lrow;
                    const int bcol = (ks * 64 + lk * 16) ^ ((brow & 7) << 4);
                    const bf16x8 bf = *(const bf16x8*)((const char*)Bc + brow * 256 + bcol);
                    accF[n] = __builtin_amdgcn_mfma_f32_16x16x32_bf16(af, bf, accF[n], 0, 0, 0);
                }
            }
#pragma unroll
            for (int n = 0; n < 2; ++n) {
                const int gcol = cc * 32 + n * 16 + ccol;
                const float bb = ffb[gcol];
#pragma unroll
                for (int j = 0; j < 4; ++j) {
                    const int grow = r0 + w * 16 + crow0 + j;
                    Fb[(size_t)grow * 64 + gcol] = f2bf(fmaxf(accF[n][j] + bb, 0.f));
                }
            }
        }
    }

    if constexpr (CKV) {
        // out[64][256] = y @ ckvW^T in 8 chunks of 32 cols; K=128 each.
        for (int cc = 0; cc < 8; ++cc) {
            __syncthreads();   // As K-loop reads done (cc=0) / prev chunk done
            for (int i = t; i < 512; i += 256) {
                const int row = i >> 4, ch = i & 15;
                *(short8*)((char*)Bc + row * 256 + ((ch * 16) ^ ((row & 7) << 4))) =
                    *(const short8*)(ckvW + (size_t)(cc * 32 + row) * 128 + ch * 8);
            }
            __syncthreads();   // y + Bc visible
            f32x4 accC[2];
#pragma unroll
            for (int n = 0; n < 2; ++n) accC[n] = (f32x4)0.f;
#pragma unroll
            for (int ks = 0; ks < 4; ++ks) {
                const int arow2 = w * 16 + lrow;
                const int acol = (ks * 64 + lk * 16) ^ ((arow2 & 7) << 4);
                const bf16x8 af = *(const bf16x8*)((const char*)Ws + arow2 * 256 + acol);
#pragma unroll
                for (int n = 0; n < 2; ++n) {
                    const int brow = n * 16 + lrow;
                    const int bcol = (ks * 64 + lk * 16) ^ ((brow & 7) << 4);
                    const bf16x8 bf = *(const bf16x8*)((const char*)Bc + brow * 256 + bcol);
                    accC[n] = __builtin_amdgcn_mfma_f32_16x16x32_bf16(af, bf, accC[n], 0, 0, 0);
                }
            }
#pragma unroll
            for (int n = 0; n < 2; ++n) {
                const int gcol = cc * 32 + n * 16 + ccol;
                const float bb = ckvB[gcol];
#pragma unroll
                for (int j = 0; j < 4; ++j) {
                    const int grow = r0 + w * 16 + crow0 + j;
                    KVout[(size_t)grow * 256 + gcol] = accC[n][j] + bb;
                }
            }
        }
    }
}

// ---------------------------------------------------------------------------
// MFMA flash attention, encoder self-attn (verified r3).
// ---------------------------------------------------------------------------
__global__ __launch_bounds__(256) void k_attn_mfma(
    const ushort* __restrict__ qkv, ushort* __restrict__ ob, float scale)
{
    __shared__ ushort Ks[208 * 40];
    __shared__ ushort Vt[32 * 232];
    __shared__ ushort Ps[4][16 * 232];
    const int bh = blockIdx.x;
    const int b = bh >> 2, h = bh & 3;
    const int t = threadIdx.x, w = t >> 6, l = t & 63;
    const int lr = l & 15, lg = l >> 4;

    for (int idx = t; idx < 784; idx += 256) {
        const int j = idx >> 2, ch = idx & 3;
        const size_t base = ((size_t)j * 256 + b) * 384 + h * 32 + ch * 8;
        *(short8*)(Ks + j * 40 + ch * 8) = *(const short8*)(qkv + base + 128);
        short8 v = *(const short8*)(qkv + base + 256);
#pragma unroll
        for (int q = 0; q < 8; ++q)
            Vt[(ch * 8 + q) * 232 + j] = (ushort)v[q];
    }
    for (int idx = t; idx < 32 * 36; idx += 256)
        Vt[(idx / 36) * 232 + 196 + (idx % 36)] = 0;
    for (int i = l; i < 256; i += 64)
        Ps[w][(i >> 4) * 232 + 208 + (i & 15)] = 0;
    __syncthreads();

    for (int qt = w; qt < 13; qt += 4) {
        int qr = qt * 16 + lr; if (qr > 195) qr = 195;
        const bf16x8 qf = *(const bf16x8*)(qkv + ((size_t)qr * 256 + b) * 384 + h * 32 + lg * 8);

        f32x4 s[13];
#pragma unroll
        for (int jn = 0; jn < 13; ++jn) {
            const bf16x8 kf = *(const bf16x8*)(Ks + (jn * 16 + lr) * 40 + lg * 8);
            s[jn] = __builtin_amdgcn_mfma_f32_16x16x32_bf16(qf, kf, (f32x4)0.f, 0, 0, 0);
        }
        if (lr >= 4) {
            s[12][0] = -3.0e38f; s[12][1] = -3.0e38f;
            s[12][2] = -3.0e38f; s[12][3] = -3.0e38f;
        }

        float inv[4];
        ushort* pw = Ps[w];
#pragma unroll
        for (int j = 0; j < 4; ++j) {
            float m = s[0][j];
#pragma unroll
            for (int jn = 1; jn < 13; ++jn) m = fmaxf(m, s[jn][j]);
            m = fmaxf(m, __shfl_xor(m, 1, 64));
            m = fmaxf(m, __shfl_xor(m, 2, 64));
            m = fmaxf(m, __shfl_xor(m, 4, 64));
            m = fmaxf(m, __shfl_xor(m, 8, 64));
            float sum = 0.f;
#pragma unroll
            for (int jn = 0; jn < 13; ++jn) {
                const float p = __expf((s[jn][j] - m) * scale);
                s[jn][j] = p;
                sum += p;
            }
            sum += __shfl_xor(sum, 1, 64);
            sum += __shfl_xor(sum, 2, 64);
            sum += __shfl_xor(sum, 4, 64);
            sum += __shfl_xor(sum, 8, 64);
            inv[j] = 1.0f / sum;
        }
#pragma unroll
        for (int jn = 0; jn < 13; ++jn)
#pragma unroll
            for (int j = 0; j < 4; ++j)
                pw[(lg * 4 + j) * 232 + jn * 16 + lr] = f2bf(s[jn][j]);

        f32x4 o0 = (f32x4)0.f, o1 = (f32x4)0.f;
#pragma unroll
        for (int kt = 0; kt < 7; ++kt) {
            const bf16x8 pf = *(const bf16x8*)(pw + lr * 232 + kt * 32 + lg * 8);
            const bf16x8 v0 = *(const bf16x8*)(Vt + lr * 232 + kt * 32 + lg * 8);
            const bf16x8 v1 = *(const bf16x8*)(Vt + (16 + lr) * 232 + kt * 32 + lg * 8);
            o0 = __builtin_amdgcn_mfma_f32_16x16x32_bf16(pf, v0, o0, 0, 0, 0);
            o1 = __builtin_amdgcn_mfma_f32_16x16x32_bf16(pf, v1, o1, 0, 0, 0);
        }
#pragma unroll
        for (int j = 0; j < 4; ++j) {
            const int r = qt * 16 + lg * 4 + j;
            if (r < 196) {
                const size_t o = ((size_t)r * 256 + b) * 128 + h * 32;
                ob[o + lr]      = f2bf(o0[j] * inv[j]);
                ob[o + 16 + lr] = f2bf(o1[j] * inv[j]);
            }
        }
    }
}

// ---------------------------------------------------------------------------
// Fused attention (f32, decoder cross path; verified r1).
// ---------------------------------------------------------------------------
__global__ __launch_bounds__(256) void k_attn(
    const float* __restrict__ qp, int qstride,
    const float* __restrict__ kvp, int kvstride, int koff, int voff,
    float* __restrict__ op, ushort* __restrict__ ob,
    int Lq, int Lk, float scale)
{
    __shared__ float Kl[196 * 36];
    __shared__ float Vl[196 * 32];
    __shared__ float pbuf[4][256];
    const int bh = blockIdx.x;
    const int b = bh >> 2;
    const int h = bh & 3;
    const int t = threadIdx.x;
    const int w = t >> 6;
    const int l = t & 63;

    for (int idx = t; idx < Lk * 8; idx += 256) {
        const int j = idx >> 3;
        const int kq = idx & 7;
        const size_t row = ((size_t)j * 256 + b) * kvstride + h * 32 + kq * 4;
        *(float4*)(&Kl[j * 36 + kq * 4]) = *(const float4*)(kvp + row + koff);
        *(float4*)(&Vl[j * 32 + kq * 4]) = *(const float4*)(kvp + row + voff);
    }
    if ((Lk & 1) && t < 8) *(float4*)(&Vl[Lk * 32 + t * 4]) = make_float4(0.f, 0.f, 0.f, 0.f);
    __syncthreads();

    const int Lh = (Lk + 1) >> 1;
    const int half = l >> 5;
    const int kk = l & 31;
    const int jb = half * Lh;

    for (int jq = w; jq < Lq; jq += 4) {
        const float* qrow = qp + ((size_t)jq * 256 + b) * qstride + h * 32;
        float4 q4[8];
#pragma unroll
        for (int kq = 0; kq < 8; ++kq) q4[kq] = *(const float4*)(qrow + kq * 4);

        float s[4];
#pragma unroll
        for (int r = 0; r < 4; ++r) {
            const int j = l + (r << 6);
            float acc = -3.0e38f;
            if (j < Lk) {
                acc = 0.f;
#pragma unroll
                for (int kq = 0; kq < 8; ++kq) {
                    const float4 kv = *(const float4*)(&Kl[j * 36 + kq * 4]);
                    acc += q4[kq].x * kv.x + q4[kq].y * kv.y +
                           q4[kq].z * kv.z + q4[kq].w * kv.w;
                }
                acc *= scale;
            }
            s[r] = acc;
        }
        float m = fmaxf(fmaxf(s[0], s[1]), fmaxf(s[2], s[3]));
        m = wred_max(m);
        float sum = 0.f;
#pragma unroll
        for (int r = 0; r < 4; ++r) {
            const int j = l + (r << 6);
            float p = __expf(s[r] - m);
            if (j >= Lk) p = 0.f;
            pbuf[w][j] = p;
            sum += p;
        }
        sum = wred_sum(sum);
        const float inv = 1.0f / sum;
        __threadfence_block();

        float o = 0.f;
        for (int jj = 0; jj < Lh; ++jj) {
            const float pv = pbuf[w][jb + jj];
            const float vv = Vl[(jb + jj) * 32 + kk];
            o += pv * vv;
        }
        o += __shfl_xor(o, 32, 64);
        o *= inv;
        if (l < 32) {
            const size_t oi = ((size_t)jq * 256 + b) * 128 + h * 32 + l;
            if (op) op[oi] = o;
            if (ob) ob[oi] = f2bf(o);
        }
        __threadfence_block();
    }
}

// ---------------------------------------------------------------------------
// Fused decoder part 2 v3 (verified r9) + L2 weight prefetch (r17).
// ---------------------------------------------------------------------------
__global__ __launch_bounds__(512) void k_dec2(
    const float* __restrict__ TGo, const float* __restrict__ AT,
    const float* __restrict__ caoW, const float* __restrict__ caob,
    const float* __restrict__ ln2s, const float* __restrict__ ln2b,
    const float* __restrict__ ff1W, const float* __restrict__ ff1b,
    const float* __restrict__ ff2W, const float* __restrict__ ff2b,
    const float* __restrict__ ln3s, const float* __restrict__ ln3b,
    const float* __restrict__ ns, const float* __restrict__ nb,
    const float* __restrict__ l1W, const float* __restrict__ l1b,
    const float* __restrict__ l2w, const float* __restrict__ l2b,
    float* __restrict__ qout)
{
    __shared__ float tg[15][128], ao[15][128], o2[15][128];
    __shared__ float ff[15][64];
    const int b = blockIdx.x, t = threadIdx.x;
    const int w = t >> 6, l = t & 63;

    {
        float pf = 0.f;
#define PFW(P, N) for (int i = t * 32; i < (N); i += 512 * 32) pf += P[i];
        PFW(caoW, 128 * 128)
        PFW(ff1W, 128 * 64)
        PFW(ff2W, 64 * 128)
        PFW(l1W, 128 * 128)
#undef PFW
        asm volatile("" :: "v"(pf));
    }

    for (int idx = t; idx < 1920; idx += 512) {
        const int r = idx >> 7, c = idx & 127;
        tg[r][c] = TGo[((size_t)r * 256 + b) * 128 + c];
        ao[r][c] = AT[((size_t)r * 256 + b) * 128 + c];
    }
    __syncthreads();

    {
        const int c = t & 127, g = t >> 7;
        const int r3 = (g + 12 < 15) ? g + 12 : 0;
        float a0 = 0.f, a1 = 0.f, a2 = 0.f, a3 = 0.f;
#pragma unroll 4
        for (int k = 0; k < 128; ++k) {
            const float wv = caoW[(size_t)k * 128 + c];
            a0 += ao[g][k] * wv;
            a1 += ao[g + 4][k] * wv;
            a2 += ao[g + 8][k] * wv;
            a3 += ao[r3][k] * wv;
        }
        const float bb = caob[c];
        o2[g][c]     = a0 + bb + tg[g][c];
        o2[g + 4][c] = a1 + bb + tg[g + 4][c];
        o2[g + 8][c] = a2 + bb + tg[g + 8][c];
        if (g + 12 < 15) o2[g + 12][c] = a3 + bb + tg[g + 12][c];
    }
    __syncthreads();
    for (int r = w; r < 15; r += 8) {
        const float x0 = o2[r][l], x1 = o2[r][l + 64];
        const float sm = wred_sum(x0 + x1);
        const float sq = wred_sum(x0 * x0 + x1 * x1);
        const float mean = sm * 0.0078125f;
        const float rstd = rsqrtf(sq * 0.0078125f - mean * mean + 1e-5f);
        tg[r][l]      = (x0 - mean) * rstd * ln2s[l] + ln2b[l];
        tg[r][l + 64] = (x1 - mean) * rstd * ln2s[l + 64] + ln2b[l + 64];
    }
    __syncthreads();
    {
        const int n = t & 63, g = t >> 6;
        const int r1 = (g + 8 < 15) ? g + 8 : 0;
        float a0 = 0.f, a1 = 0.f;
#pragma unroll 4
        for (int k = 0; k < 128; ++k) {
            const float wv = ff1W[(size_t)k * 64 + n];
            a0 += tg[g][k] * wv;
            a1 += tg[r1][k] * wv;
        }
        const float bb = ff1b[n];
        ff[g][n] = fmaxf(a0 + bb, 0.f);
        if (g + 8 < 15) ff[g + 8][n] = fmaxf(a1 + bb, 0.f);
    }
    __syncthreads();
    {
        const int c = t & 127, g = t >> 7;
        const int r3 = (g + 12 < 15) ? g + 12 : 0;
        float a0 = 0.f, a1 = 0.f, a2 = 0.f, a3 = 0.f;
#pragma unroll 4
        for (int k = 0; k < 64; ++k) {
            const float wv = ff2W[(size_t)k * 128 + c];
            a0 += ff[g][k] * wv;
            a1 += ff[g + 4][k] * wv;
            a2 += ff[g + 8][k] * wv;
            a3 += ff[r3][k] * wv;
        }
        const float bb = ff2b[c];
        o2[g][c]     = a0 + bb + tg[g][c];
        o2[g + 4][c] = a1 + bb + tg[g + 4][c];
        o2[g + 8][c] = a2 + bb + tg[g + 8][c];
        if (g + 12 < 15) o2[g + 12][c] = a3 + bb + tg[g + 12][c];
    }
    __syncthreads();
    for (int r = w; r < 15; r += 8) {
        const float x0 = o2[r][l], x1 = o2[r][l + 64];
        const float sm = wred_sum(x0 + x1);
        const float sq = wred_sum(x0 * x0 + x1 * x1);
        const float mean = sm * 0.0078125f;
        const float rstd = rsqrtf(sq * 0.0078125f - mean * mean + 1e-5f);
        const float y0 = (x0 - mean) * rstd * ln3s[l] + ln3b[l];
        const float y1 = (x1 - mean) * rstd * ln3s[l + 64] + ln3b[l + 64];
        const float sm2 = wred_sum(y0 + y1);
        const float sq2 = wred_sum(y0 * y0 + y1 * y1);
        const float mean2 = sm2 * 0.0078125f;
        const float rstd2 = rsqrtf(sq2 * 0.0078125f - mean2 * mean2 + 1e-5f);
        tg[r][l]      = (y0 - mean2) * rstd2 * ns[l] + nb[l];
        tg[r][l + 64] = (y1 - mean2) * rstd2 * ns[l + 64] + nb[l + 64];
    }
    __syncthreads();
    {
        const int c = t & 127, g = t >> 7;
        const int r3 = (g + 12 < 15) ? g + 12 : 0;
        float a0 = 0.f, a1 = 0.f, a2 = 0.f, a3 = 0.f;
#pragma unroll 4
        for (int k = 0; k < 128; ++k) {
            const float wv = l1W[(size_t)k * 128 + c];
            a0 += tg[g][k] * wv;
            a1 += tg[g + 4][k] * wv;
            a2 += tg[g + 8][k] * wv;
            a3 += tg[r3][k] * wv;
        }
        const float bb = l1b[c];
        o2[g][c]     = fmaxf(a0 + bb, 0.f);
        o2[g + 4][c] = fmaxf(a1 + bb, 0.f);
        o2[g + 8][c] = fmaxf(a2 + bb, 0.f);
        if (g + 12 < 15) o2[g + 12][c] = fmaxf(a3 + bb, 0.f);
    }
    __syncthreads();
    for (int r = w; r < 15; r += 8) {
        const float d = wred_sum(o2[r][l] * l2w[l] + o2[r][l + 64] * l2w[l + 64]);
        if (l == 0) qout[b * 15 + r] = d + l2b[0];
    }
}

// ---------------------------------------------------------------------------
extern "C" void kernel_launch(void* const* d_in, const int* in_sizes, int n_in,
                              void* d_out, int out_size, void* d_ws, size_t ws_size,
                              hipStream_t stream)
{
    (void)in_sizes; (void)n_in; (void)out_size; (void)ws_size;
    const float* image      = (const float*)d_in[0];
    const float* angle      = (const float*)d_in[1];
    const float* pos_x      = (const float*)d_in[2];
    const float* pos_y      = (const float*)d_in[3];
    const float* sk         = (const float*)d_in[4];
    const float* patch_W    = (const float*)d_in[5];
    const float* patch_b    = (const float*)d_in[6];
    const float* pos_emb    = (const float*)d_in[7];
    const float* enc_qkv_W  = (const float*)d_in[8];
    const float* enc_qkv_b  = (const float*)d_in[9];
    const float* enc_out_W  = (const float*)d_in[10];
    const float* enc_out_b  = (const float*)d_in[11];
    const float* enc_ln1_s  = (const float*)d_in[12];
    const float* enc_ln1_b  = (const float*)d_in[13];
    const float* enc_ff1_W  = (const float*)d_in[14];
    const float* enc_ff1_b  = (const float*)d_in[15];
    const float* enc_ff2_W  = (const float*)d_in[16];
    const float* enc_ff2_b  = (const float*)d_in[17];
    const float* enc_ln2_s  = (const float*)d_in[18];
    const float* enc_ln2_b  = (const float*)d_in[19];
    const float* dec_sa_qkv_W = (const float*)d_in[20];
    const float* dec_sa_qkv_b = (const float*)d_in[21];
    const float* dec_sa_out_W = (const float*)d_in[22];
    const float* dec_sa_out_b = (const float*)d_in[23];
    const float* dec_ca_qkv_W = (const float*)d_in[24];
    const float* dec_ca_qkv_b = (const float*)d_in[25];
    const float* dec_ca_out_W = (const float*)d_in[26];
    const float* dec_ca_out_b = (const float*)d_in[27];
    const float* dec_ln1_s  = (const float*)d_in[28];
    const float* dec_ln1_b  = (const float*)d_in[29];
    const float* dec_ln2_s  = (const float*)d_in[30];
    const float* dec_ln2_b  = (const float*)d_in[31];
    const float* dec_ln3_s  = (const float*)d_in[32];
    const float* dec_ln3_b  = (const float*)d_in[33];
    const float* dec_ff1_W  = (const float*)d_in[34];
    const float* dec_ff1_b  = (const float*)d_in[35];
    const float* dec_ff2_W  = (const float*)d_in[36];
    const float* dec_ff2_b  = (const float*)d_in[37];
    const float* dec_norm_s = (const float*)d_in[38];
    const float* dec_norm_b = (const float*)d_in[39];
    const float* sk1_W = (const float*)d_in[40];
    const float* sk1_b = (const float*)d_in[41];
    const float* sk2_W = (const float*)d_in[42];
    const float* sk2_b = (const float*)d_in[43];
    const float* sk3_W = (const float*)d_in[44];
    const float* sk3_b = (const float*)d_in[45];
    const float* act_W = (const float*)d_in[46];
    const float* act_b = (const float*)d_in[47];
    const float* l1_W  = (const float*)d_in[48];
    const float* l1_b  = (const float*)d_in[49];
    const float* l2_W  = (const float*)d_in[50];
    const float* l2_b  = (const float*)d_in[51];

    // Workspace (float offsets)
    float* ws = (float*)d_ws;
    float* S0   = ws;               // src f32 residual stream  [6,422,528]
    float* QKVr = ws + 6422528;     // big overlay region       [19,267,584]
    float* T0   = ws + 25690112;    // decoder cross-attn out   [6,422,528]
    float* T1   = ws + 32112640;    // (spare)                  [6,422,528]
    float* F1   = ws + 38535168;    // F1b bf16                 [3,211,264]
    float* M0r  = ws + 41746432;    // T0b bf16                 [6,422,528]
    float* S1s  = ws + 48168960;
    float* TG   = S1s + 156672;     // tgt f32 15*256*128
    ushort* WTS = (ushort*)(ws + 48817152);

    // Overlays
    ushort* QKVb = (ushort*)QKVr;            // enc QKV bf16 [50176][384]
    float*  KV   = QKVr;                     // cross K/V f32 [50176][256]
    float* DQ   = QKVr + 14319616;           // dec cross Q f32
    float* DT0  = T0;
    ushort* T0b  = (ushort*)M0r;
    ushort* F1b  = (ushort*)F1;
    ushort* wt_patch = WTS;
    ushort* wt_qkv   = WTS + 98304;
    ushort* wt_out   = WTS + 147456;
    ushort* wt_ff1   = WTS + 163840;
    ushort* wt_ff2   = WTS + 172032;
    ushort* wt_ckv   = WTS + 180224;
    (void)T1;

    const float rs = 0.17677669529663687f;  // 1/sqrt(32)

    // ---- prep ----
    k_wconv<<<dim3(832), 256, 0, stream>>>(patch_W, enc_qkv_W, enc_out_W,
                                           enc_ff1_W, enc_ff2_W, dec_ca_qkv_W, WTS);

    // ---- merged dec1 + patchify-GEMM + fused QKV (r19-verbatim) ----
    k_pg_dec1<<<dim3(1040), 512, 49152, stream>>>(
        image, wt_patch, patch_b, pos_emb, S0,
        wt_qkv, enc_qkv_b, QKVb,
        sk, sk1_W, sk1_b, sk2_W, sk2_b, sk3_W, sk3_b,
        angle, pos_x, pos_y, act_W, act_b,
        dec_sa_qkv_W, dec_sa_qkv_b, dec_sa_out_W, dec_sa_out_b,
        dec_ln1_s, dec_ln1_b, dec_ca_qkv_W, dec_ca_qkv_b, TG, DQ);

    // ---- encoder ----
    k_attn_mfma<<<dim3(1024), 256, 0, stream>>>(QKVb, T0b, rs);
    k_gemm_ln<1, 0><<<dim3(784), 256, 0, stream>>>(           // out-proj + LN1 + FF1
        T0b, 128, wt_out, 128, enc_out_b, S0, enc_ln1_s, enc_ln1_b, S0, nullptr,
        wt_ff1, enc_ff1_b, F1b, nullptr, nullptr, nullptr);
    k_gemm_ln<0, 1><<<dim3(784), 256, 0, stream>>>(           // FF2 + LN2 + cross-KV
        F1b, 64, wt_ff2, 64, enc_ff2_b, S0, enc_ln2_s, enc_ln2_b, nullptr, nullptr,
        nullptr, nullptr, nullptr, wt_ckv, dec_ca_qkv_b + 128, KV);

    // ---- decoder cross-attn + tail ----
    k_attn<<<dim3(1024), 256, 0, stream>>>(DQ, 128, KV, 256, 0, 128,
                                           DT0, nullptr, 15, 196, rs);
    k_dec2<<<dim3(256), 512, 0, stream>>>(
        TG, DT0, dec_ca_out_W, dec_ca_out_b, dec_ln2_s, dec_ln2_b,
        dec_ff1_W, dec_ff1_b, dec_ff2_W, dec_ff2_b,
        dec_ln3_s, dec_ln3_b, dec_norm_s, dec_norm_b,
        l1_W, l1_b, l2_W, l2_b, (float*)d_out);
}

// Round 22
// 278.421 us; speedup vs baseline: 1.0178x; 1.0178x over previous
//
#include <hip/hip_runtime.h>
#include <math.h>

#define BSZ 256
#define DIM 128
#define NHD 4
#define NPATCH 196
#define NACT 15

typedef float f32x4 __attribute__((ext_vector_type(4)));
typedef __bf16 bf16x8 __attribute__((ext_vector_type(8)));
typedef short short8 __attribute__((ext_vector_type(8)));

__device__ __forceinline__ float wred_sum(float v) {
#pragma unroll
    for (int m = 1; m < 64; m <<= 1) v += __shfl_xor(v, m, 64);
    return v;
}
__device__ __forceinline__ float wred_max(float v) {
#pragma unroll
    for (int m = 1; m < 64; m <<= 1) v = fmaxf(v, __shfl_xor(v, m, 64));
    return v;
}
__device__ __forceinline__ ushort f2bf(float f) {  // RNE bf16
    unsigned u = __float_as_uint(f);
    return (ushort)((u + 0x7fffu + ((u >> 16) & 1u)) >> 16);
}
__device__ __forceinline__ float bf2f(ushort u) {
    return __uint_as_float((unsigned)u << 16);
}

// ---------------------------------------------------------------------------
// Weight convert+transpose to bf16 [N][K] (patch K-permuted), packed.
// ---------------------------------------------------------------------------
__global__ __launch_bounds__(256) void k_wconv(
    const float* __restrict__ pW, const float* __restrict__ qkvW,
    const float* __restrict__ outW, const float* __restrict__ ff1W,
    const float* __restrict__ ff2W, const float* __restrict__ ckvW,
    ushort* __restrict__ o)
{
    int i = blockIdx.x * 256 + threadIdx.x;
    if (i < 98304) {
        int n = i / 768, kp = i % 768;
        int c = kp >> 8, q = kp & 255;
        o[i] = f2bf(pW[(q * 3 + c) * 128 + n]); return;
    }
    i -= 98304;
    if (i < 49152) { int n = i >> 7, k = i & 127; o[98304 + i] = f2bf(qkvW[k * 384 + n]); return; }
    i -= 49152;
    if (i < 16384) { int n = i >> 7, k = i & 127; o[147456 + i] = f2bf(outW[k * 128 + n]); return; }
    i -= 16384;
    if (i < 8192)  { int n = i >> 7, k = i & 127; o[163840 + i] = f2bf(ff1W[k * 64 + n]); return; }
    i -= 8192;
    if (i < 8192)  { int n = i >> 6, k = i & 63;  o[172032 + i] = f2bf(ff2W[k * 128 + n]); return; }
    i -= 8192;
    if (i < 32768) { int n = i >> 7, k = i & 127; o[180224 + i] = f2bf(ckvW[k * 384 + 128 + n]); return; }
}

// ---------------------------------------------------------------------------
// MERGED kernel (verified r18/r19): blocks [0,256) = dec1 (L2 prefetch);
// blocks [256,1040) = patchify-GEMM + fused encoder-QKV stage.
// ---------------------------------------------------------------------------
__global__ __launch_bounds__(512) void k_pg_dec1(
    const float* __restrict__ img, const ushort* __restrict__ Wt,
    const float* __restrict__ pbias, const float* __restrict__ pe,
    float* __restrict__ C,
    const ushort* __restrict__ qkvWt, const float* __restrict__ qkvB,
    ushort* __restrict__ QKVb,
    const float* __restrict__ sk,
    const float* __restrict__ W1, const float* __restrict__ b1,
    const float* __restrict__ W2, const float* __restrict__ b2,
    const float* __restrict__ W3, const float* __restrict__ b3,
    const float* __restrict__ ang, const float* __restrict__ px,
    const float* __restrict__ py,
    const float* __restrict__ actW, const float* __restrict__ actb,
    const float* __restrict__ saW, const float* __restrict__ sab,
    const float* __restrict__ saoW, const float* __restrict__ saob,
    const float* __restrict__ ln1s, const float* __restrict__ ln1b,
    const float* __restrict__ caW, const float* __restrict__ cab,
    float* __restrict__ TGo, float* __restrict__ DQ)
{
    extern __shared__ char smem[];
    const int t = threadIdx.x;
    const int w = t >> 6, l = t & 63;

    if (blockIdx.x >= 256) {
        ushort* As = (ushort*)smem;          // 16 KB (2 x 64x64)
        ushort* Ws = As + 2 * 64 * 64;       // 32 KB (2 x 128x64)
        const bool act = t < 256;
        const int pb = blockIdx.x - 256;
        const int p = pb >> 2, bq = pb & 3;
        const int hp_ = p / 14, wp = p % 14;
        const int r0 = p * 256 + bq * 64;
        const int wm = w >> 1, wn = w & 1;
        const int lrow = l & 15, lk = l >> 4;
        const int arow = (t & 255) >> 2;
        const int b_img = bq * 64 + arow;
        const float* gimg = img + (size_t)b_img * 150528 + hp_ * 3584 + wp * 16;

        f32x4 acc[2][4];
#pragma unroll
        for (int m = 0; m < 2; ++m)
#pragma unroll
            for (int n = 0; n < 4; ++n) acc[m][n] = (f32x4)0.f;

        float4 va[4];
        short8 wr[4];

        auto loadT = [&](int kc) {
            if (!act) return;
            const int c = kc >> 8, p1q = (kc >> 6) & 3;
            const float* gc = gimg + c * 50176 + p1q * 896;
#pragma unroll
            for (int i = 0; i < 4; ++i)
                va[i] = *(const float4*)(gc + i * 224 + (t & 3) * 4);
#pragma unroll
            for (int j = 0; j < 4; ++j) {
                const int i2 = t + 256 * j;
                const int row = i2 >> 3, ch = i2 & 7;
                wr[j] = *(const short8*)(Wt + (size_t)row * 768 + kc + ch * 8);
            }
        };
        auto storeT = [&](int buf) {
            if (!act) return;
            ushort* Ab = As + buf * 64 * 64;
            ushort* Wb = Ws + buf * 128 * 64;
#pragma unroll
            for (int i = 0; i < 4; ++i) {
                ushort4 o4;
                o4.x = f2bf(va[i].x); o4.y = f2bf(va[i].y);
                o4.z = f2bf(va[i].z); o4.w = f2bf(va[i].w);
                const int kq = (t & 3) + 4 * i;
                const int bo = (kq * 8) ^ ((arow & 7) << 4);
                *(ushort4*)((char*)Ab + arow * 128 + bo) = o4;
            }
#pragma unroll
            for (int j = 0; j < 4; ++j) {
                const int i2 = t + 256 * j;
                const int row = i2 >> 3, ch = i2 & 7;
                const int sw = (ch * 16) ^ ((row & 7) << 4);
                *(short8*)((char*)Wb + row * 128 + sw) = wr[j];
            }
        };
        auto mfmaT = [&](int buf) {
            if (!act) return;
            const ushort* Ab = As + buf * 64 * 64;
            const ushort* Wb = Ws + buf * 128 * 64;
#pragma unroll
            for (int ks = 0; ks < 2; ++ks) {
                bf16x8 af[2], bfr[4];
#pragma unroll
                for (int m = 0; m < 2; ++m) {
                    const int row = wm * 32 + m * 16 + lrow;
                    const int col = (ks * 64 + lk * 16) ^ ((row & 7) << 4);
                    af[m] = *(const bf16x8*)((const char*)Ab + row * 128 + col);
                }
#pragma unroll
                for (int n = 0; n < 4; ++n) {
                    const int row = wn * 64 + n * 16 + lrow;
                    const int col = (ks * 64 + lk * 16) ^ ((row & 7) << 4);
                    bfr[n] = *(const bf16x8*)((const char*)Wb + row * 128 + col);
                }
#pragma unroll
                for (int m = 0; m < 2; ++m)
#pragma unroll
                    for (int n = 0; n < 4; ++n)
                        acc[m][n] = __builtin_amdgcn_mfma_f32_16x16x32_bf16(
                            af[m], bfr[n], acc[m][n], 0, 0, 0);
            }
        };

        loadT(0);
        for (int it = 0; it < 12; it += 2) {
            storeT(0);
            if (it + 1 < 12) loadT((it + 1) * 64);
            __syncthreads();
            mfmaT(0);
            storeT(1);
            if (it + 2 < 12) loadT((it + 2) * 64);
            __syncthreads();
            mfmaT(1);
        }

        __syncthreads();
        const int crow0 = (l >> 4) * 4;
        const int ccol = l & 15;
        if (act) {
#pragma unroll
            for (int m = 0; m < 2; ++m) {
                const int rowb = wm * 32 + m * 16 + crow0;
#pragma unroll
                for (int n = 0; n < 4; ++n) {
                    const int col = wn * 64 + n * 16 + ccol;
                    const float bv = pbias[col] + pe[p * 128 + col];
#pragma unroll
                    for (int j = 0; j < 4; ++j) {
                        const int row = rowb + j;
                        const float v = acc[m][n][j] + bv;
                        C[(size_t)(r0 + row) * 128 + col] = v;
                        const int bo = row * 256 + (((col >> 3) * 16) ^ ((row & 7) << 4)) + (col & 7) * 2;
                        *(ushort*)((char*)As + bo) = f2bf(v);
                    }
                }
            }
        }

        // ---- fused QKV stage (verified r18) ----
        const int wm2 = w >> 1;
        const int wn2 = w & 1;
        for (int cc = 0; cc < 3; ++cc) {
            __syncthreads();
            for (int i = t; i < 2048; i += 512) {
                const int row = i >> 4, ch = i & 15;
                *(short8*)((char*)Ws + row * 256 + ((ch * 16) ^ ((row & 7) << 4))) =
                    *(const short8*)(qkvWt + (size_t)(cc * 128 + row) * 128 + ch * 8);
            }
            __syncthreads();
            f32x4 a2[4];
#pragma unroll
            for (int n = 0; n < 4; ++n) a2[n] = (f32x4)0.f;
#pragma unroll
            for (int ks = 0; ks < 4; ++ks) {
                const int arow2 = wm2 * 16 + lrow;
                const int acol = (ks * 64 + lk * 16) ^ ((arow2 & 7) << 4);
                const bf16x8 af = *(const bf16x8*)((const char*)As + arow2 * 256 + acol);
#pragma unroll
                for (int n = 0; n < 4; ++n) {
                    const int brow = wn2 * 64 + n * 16 + lrow;
                    const int bcol = (ks * 64 + lk * 16) ^ ((brow & 7) << 4);
                    const bf16x8 bf = *(const bf16x8*)((const char*)Ws + brow * 256 + bcol);
                    a2[n] = __builtin_amdgcn_mfma_f32_16x16x32_bf16(af, bf, a2[n], 0, 0, 0);
                }
            }
#pragma unroll
            for (int n = 0; n < 4; ++n) {
                const int gcol = cc * 128 + wn2 * 64 + n * 16 + ccol;
                const float bb = qkvB[gcol];
#pragma unroll
                for (int j = 0; j < 4; ++j) {
                    const int grow = r0 + wm2 * 16 + crow0 + j;
                    QKVb[(size_t)grow * 384 + gcol] = f2bf(a2[n][j] + bb);
                }
            }
        }
        return;
    }

    // ================= dec1 body (r17-verbatim, incl. L2 prefetch) ==========
    float* tg  = (float*)smem;
    float* qkv = tg + 1920;
    float* ao  = qkv + 5820;
    float* xr  = ao + 1920;
    float* h1  = xr + 256;
    float* h2  = h1 + 256;
    float* s3  = h2 + 256;
    float* pbv = s3 + 100;
    float* hp  = pbv + 64;
    const int b = blockIdx.x;

    {
        float pf = 0.f;
#define PFW(P, N) for (int i = t * 32; i < (N); i += 512 * 32) pf += P[i];
        PFW(W1, 200 * 256)
        PFW(W2, 256 * 256)
        PFW(W3, 256 * 100)
        PFW(actW, 118 * 128)
        PFW(saW, 128 * 384)
        PFW(saoW, 128 * 128)
        PFW(caW, 128 * 384)
#undef PFW
        asm volatile("" :: "v"(pf));
    }

    if (t < 256) xr[t] = (t < 200) ? sk[(size_t)b * 200 + t] : 0.f;
    __syncthreads();
    {
        const int c = t & 255, g = t >> 8;
        const int k0 = g * 100;
        float a = 0.f;
#pragma unroll 10
        for (int k = k0; k < k0 + 100; ++k) a += xr[k] * W1[k * 256 + c];
        hp[g * 256 + c] = a;
    }
    __syncthreads();
    if (t < 256) h1[t] = fmaxf(hp[t] + hp[256 + t] + b1[t], 0.f);
    __syncthreads();
    {
        const int c = t & 255, g = t >> 8;
        const int k0 = g * 128;
        float a = 0.f;
#pragma unroll 8
        for (int k = k0; k < k0 + 128; ++k) a += h1[k] * W2[k * 256 + c];
        hp[g * 256 + c] = a;
    }
    __syncthreads();
    if (t < 256) h2[t] = fmaxf(hp[t] + hp[256 + t] + b2[t], 0.f);
    __syncthreads();
    if (t < 400) {
        const int c = t % 100, g = t / 100;
        const int k0 = g * 64;
        float a = 0.f;
#pragma unroll 8
        for (int k = k0; k < k0 + 64; ++k) a += h2[k] * W3[k * 100 + c];
        hp[g * 256 + c] = a;
    }
    __syncthreads();
    if (t < 100) s3[t] = hp[t] + hp[256 + t] + hp[512 + t] + hp[768 + t] + b3[t];
    __syncthreads();
    {
        const int c = t & 127, g = t >> 7;
        const int k0 = g * 25;
        float a = 0.f;
#pragma unroll 5
        for (int k = k0; k < k0 + 25; ++k) a += s3[k] * actW[(18 + k) * 128 + c];
        hp[g * 256 + c] = a;
    }
    __syncthreads();
    if (t < 128) {
        const float base = actb[t] + hp[t] + hp[256 + t] + hp[512 + t] + hp[768 + t] +
                           ang[b] * actW[15 * 128 + t] + px[b] * actW[16 * 128 + t] +
                           py[b] * actW[17 * 128 + t];
#pragma unroll
        for (int i = 0; i < 15; ++i) tg[i * 128 + t] = base + actW[i * 128 + t];
    }
    __syncthreads();

    if (t < 384) {
        float acc[15];
#pragma unroll
        for (int r = 0; r < 15; ++r) acc[r] = 0.f;
#pragma unroll 4
        for (int k = 0; k < 128; ++k) {
            const float wv = saW[(size_t)k * 384 + t];
#pragma unroll
            for (int r = 0; r < 15; ++r) acc[r] += tg[r * 128 + k] * wv;
        }
        const float bb = sab[t];
#pragma unroll
        for (int r = 0; r < 15; ++r) qkv[r * 388 + t] = acc[r] + bb;
    }
    __syncthreads();

    const float rs = 0.17677669529663687f;
    if (w < 4) {
        for (int qi = 0; qi < 15; ++qi) {
            float s = -3.0e38f;
            if (l < 15) {
                s = 0.f;
#pragma unroll
                for (int d = 0; d < 32; ++d)
                    s += qkv[qi * 388 + w * 32 + d] * qkv[l * 388 + 128 + w * 32 + d];
                s *= rs;
            }
            const float m = wred_max(s);
            const float pv = (l < 15) ? __expf(s - m) : 0.f;
            const float sum = wred_sum(pv);
            if (l < 15) pbv[w * 16 + l] = pv;
            if (l < 32) {
                float o = 0.f;
#pragma unroll
                for (int j = 0; j < 15; ++j) o += pbv[w * 16 + j] * qkv[j * 388 + 256 + w * 32 + l];
                ao[qi * 128 + w * 32 + l] = o / sum;
            }
        }
    }
    __syncthreads();

    {
        const int c = t & 127, g = t >> 7;
        const int r3 = (g + 12 < 15) ? g + 12 : 0;
        float a0 = 0.f, a1 = 0.f, a2 = 0.f, a3 = 0.f;
#pragma unroll 4
        for (int k = 0; k < 128; ++k) {
            const float wv = saoW[(size_t)k * 128 + c];
            a0 += ao[g * 128 + k] * wv;
            a1 += ao[(g + 4) * 128 + k] * wv;
            a2 += ao[(g + 8) * 128 + k] * wv;
            a3 += ao[r3 * 128 + k] * wv;
        }
        const float bb = saob[c];
        qkv[g * 388 + c]       = a0 + bb + tg[g * 128 + c];
        qkv[(g + 4) * 388 + c] = a1 + bb + tg[(g + 4) * 128 + c];
        qkv[(g + 8) * 388 + c] = a2 + bb + tg[(g + 8) * 128 + c];
        if (g + 12 < 15) qkv[(g + 12) * 388 + c] = a3 + bb + tg[(g + 12) * 128 + c];
    }
    __syncthreads();
    for (int r = w; r < 15; r += 8) {
        const float x0 = qkv[r * 388 + l], x1 = qkv[r * 388 + l + 64];
        const float sm = wred_sum(x0 + x1);
        const float sq = wred_sum(x0 * x0 + x1 * x1);
        const float mean = sm * 0.0078125f;
        const float rstd = rsqrtf(sq * 0.0078125f - mean * mean + 1e-5f);
        const float y0 = (x0 - mean) * rstd * ln1s[l] + ln1b[l];
        const float y1 = (x1 - mean) * rstd * ln1s[l + 64] + ln1b[l + 64];
        tg[r * 128 + l] = y0; tg[r * 128 + l + 64] = y1;
        float* g2 = TGo + ((size_t)r * 256 + b) * 128;
        g2[l] = y0; g2[l + 64] = y1;
    }
    __syncthreads();

    {
        const int c = t & 127, g = t >> 7;
        const int r3 = (g + 12 < 15) ? g + 12 : 0;
        float a0 = 0.f, a1 = 0.f, a2 = 0.f, a3 = 0.f;
#pragma unroll 4
        for (int k = 0; k < 128; ++k) {
            const float wv = caW[(size_t)k * 384 + c];
            a0 += tg[g * 128 + k] * wv;
            a1 += tg[(g + 4) * 128 + k] * wv;
            a2 += tg[(g + 8) * 128 + k] * wv;
            a3 += tg[r3 * 128 + k] * wv;
        }
        const float bb = cab[c];
        DQ[((size_t)g * 256 + b) * 128 + c]       = a0 + bb;
        DQ[((size_t)(g + 4) * 256 + b) * 128 + c] = a1 + bb;
        DQ[((size_t)(g + 8) * 256 + b) * 128 + c] = a2 + bb;
        if (g + 12 < 15) DQ[((size_t)(g + 12) * 256 + b) * 128 + c] = a3 + bb;
    }
}

// ---------------------------------------------------------------------------
// bf16 MFMA GEMM 64x128 + residual + LayerNorm fused epilogue (verified r5);
// optional fused FF1 stage (FF=1, verified r13); optional fused cross-KV
// stage (CKV=1, verified r19) — NOW writing KV as bf16 (storage-only change).
// ---------------------------------------------------------------------------
template <int FF, int CKV>
__global__ __launch_bounds__(256) void k_gemm_ln(
    const ushort* __restrict__ A, int lda,
    const ushort* __restrict__ Wt, int K,
    const float* __restrict__ bias,
    const float* __restrict__ resid,
    const float* __restrict__ lns, const float* __restrict__ lnbi,
    float* __restrict__ Co, ushort* __restrict__ Cb,
    const ushort* __restrict__ ffW, const float* __restrict__ ffb,
    ushort* __restrict__ Fb,
    const ushort* __restrict__ ckvW, const float* __restrict__ ckvB,
    ushort* __restrict__ KVb)
{
    __shared__ ushort As[64 * 64];
    __shared__ ushort Ws[128 * 64];          // K-loop W tiles; later y[64][256B]
    __shared__ float psum[64][2][2];
    __shared__ ushort ffWs[FF ? 64 * 128 : 2];
    __shared__ ushort ckvWs[CKV ? 64 * 128 : 2];
    const int t = threadIdx.x;
    const int w = t >> 6, l = t & 63;
    const int r0 = blockIdx.x * 64;
    const int wm = w >> 1, wn = w & 1;
    const int lrow = l & 15, lk = l >> 4;

    f32x4 acc[2][4];
#pragma unroll
    for (int m = 0; m < 2; ++m)
#pragma unroll
        for (int n = 0; n < 4; ++n) acc[m][n] = (f32x4)0.f;

    for (int kc = 0; kc < K; kc += 64) {
        __syncthreads();
#pragma unroll
        for (int i = t; i < 64 * 8; i += 256) {
            const int row = i >> 3, ch = i & 7;
            const int sw = (ch * 16) ^ ((row & 7) << 4);
            *(short8*)((char*)As + row * 128 + sw) =
                *(const short8*)(A + (size_t)(r0 + row) * lda + kc + ch * 8);
        }
#pragma unroll
        for (int i = t; i < 128 * 8; i += 256) {
            const int row = i >> 3, ch = i & 7;
            const int sw = (ch * 16) ^ ((row & 7) << 4);
            *(short8*)((char*)Ws + row * 128 + sw) =
                *(const short8*)(Wt + (size_t)row * K + kc + ch * 8);
        }
        __syncthreads();
#pragma unroll
        for (int ks = 0; ks < 2; ++ks) {
            bf16x8 af[2], bfr[4];
#pragma unroll
            for (int m = 0; m < 2; ++m) {
                const int row = wm * 32 + m * 16 + lrow;
                const int col = (ks * 64 + lk * 16) ^ ((row & 7) << 4);
                af[m] = *(const bf16x8*)((const char*)As + row * 128 + col);
            }
#pragma unroll
            for (int n = 0; n < 4; ++n) {
                const int row = wn * 64 + n * 16 + lrow;
                const int col = (ks * 64 + lk * 16) ^ ((row & 7) << 4);
                bfr[n] = *(const bf16x8*)((const char*)Ws + row * 128 + col);
            }
#pragma unroll
            for (int m = 0; m < 2; ++m)
#pragma unroll
                for (int n = 0; n < 4; ++n)
                    acc[m][n] = __builtin_amdgcn_mfma_f32_16x16x32_bf16(
                        af[m], bfr[n], acc[m][n], 0, 0, 0);
        }
    }

    const int crow0 = (l >> 4) * 4;
    const int ccol = l & 15;
#pragma unroll
    for (int m = 0; m < 2; ++m) {
        const int growb = r0 + wm * 32 + m * 16 + crow0;
#pragma unroll
        for (int n = 0; n < 4; ++n) {
            const int gcol = wn * 64 + n * 16 + ccol;
            const float bv = bias[gcol];
#pragma unroll
            for (int j = 0; j < 4; ++j) {
                float v = acc[m][n][j] + bv;
                if (resid) v += resid[(size_t)(growb + j) * 128 + gcol];
                acc[m][n][j] = v;
            }
        }
    }
#pragma unroll
    for (int m = 0; m < 2; ++m)
#pragma unroll
        for (int j = 0; j < 4; ++j) {
            float s_ = 0.f, q_ = 0.f;
#pragma unroll
            for (int n = 0; n < 4; ++n) {
                const float x = acc[m][n][j];
                s_ += x; q_ += x * x;
            }
#pragma unroll
            for (int mk = 1; mk < 16; mk <<= 1) {
                s_ += __shfl_xor(s_, mk, 64);
                q_ += __shfl_xor(q_, mk, 64);
            }
            if (ccol == 0) {
                const int r = wm * 32 + m * 16 + crow0 + j;
                psum[r][wn][0] = s_;
                psum[r][wn][1] = q_;
            }
        }
    __syncthreads();   // psum ready; all K-loop reads of Ws complete
    float mean_[2][4], rstd_[2][4];
#pragma unroll
    for (int m = 0; m < 2; ++m)
#pragma unroll
        for (int j = 0; j < 4; ++j) {
            const int r = wm * 32 + m * 16 + crow0 + j;
            const float sum = psum[r][0][0] + psum[r][1][0];
            const float sq  = psum[r][0][1] + psum[r][1][1];
            const float mean = sum * 0.0078125f;
            const float var = sq * 0.0078125f - mean * mean;
            mean_[m][j] = mean;
            rstd_[m][j] = rsqrtf(var + 1e-5f);
        }
#pragma unroll
    for (int m = 0; m < 2; ++m) {
        const int growb = r0 + wm * 32 + m * 16 + crow0;
#pragma unroll
        for (int n = 0; n < 4; ++n) {
            const int gcol = wn * 64 + n * 16 + ccol;
            const float sv = lns[gcol], bv2 = lnbi[gcol];
#pragma unroll
            for (int j = 0; j < 4; ++j) {
                const float y = (acc[m][n][j] - mean_[m][j]) * rstd_[m][j] * sv + bv2;
                acc[m][n][j] = y;
                const size_t oi = (size_t)(growb + j) * 128 + gcol;
                if (Co) Co[oi] = y;
                if (Cb) Cb[oi] = f2bf(y);
            }
        }
    }

    if constexpr (FF || CKV) {
        // Restage y (bf16) into Ws reinterpreted as [64 rows][256 B], swizzled.
#pragma unroll
        for (int m = 0; m < 2; ++m) {
            const int rowb = wm * 32 + m * 16 + crow0;
#pragma unroll
            for (int n = 0; n < 4; ++n) {
                const int c = wn * 64 + n * 16 + ccol;
                const int cb = ((c >> 3) * 16);
#pragma unroll
                for (int j = 0; j < 4; ++j) {
                    const int row = rowb + j;
                    const int bo = row * 256 + ((cb) ^ ((row & 7) << 4)) + (c & 7) * 2;
                    *(ushort*)((char*)Ws + bo) = f2bf(acc[m][n][j]);
                }
            }
        }
    }

    if constexpr (FF) {
        for (int i = t; i < 1024; i += 256) {
            const int row = i >> 4, ch = i & 15;
            *(short8*)((char*)ffWs + row * 256 + ((ch * 16) ^ ((row & 7) << 4))) =
                *(const short8*)(ffW + (size_t)row * 128 + ch * 8);
        }
        __syncthreads();
        f32x4 accF[4];
#pragma unroll
        for (int n = 0; n < 4; ++n) accF[n] = (f32x4)0.f;
#pragma unroll
        for (int ks = 0; ks < 4; ++ks) {
            const int arow2 = w * 16 + lrow;
            const int acol = (ks * 64 + lk * 16) ^ ((arow2 & 7) << 4);
            const bf16x8 af = *(const bf16x8*)((const char*)Ws + arow2 * 256 + acol);
#pragma unroll
            for (int n = 0; n < 4; ++n) {
                const int brow = n * 16 + lrow;
                const int bcol = (ks * 64 + lk * 16) ^ ((brow & 7) << 4);
                const bf16x8 bf = *(const bf16x8*)((const char*)ffWs + brow * 256 + bcol);
                accF[n] = __builtin_amdgcn_mfma_f32_16x16x32_bf16(af, bf, accF[n], 0, 0, 0);
            }
        }
#pragma unroll
        for (int n = 0; n < 4; ++n) {
            const int gcol = n * 16 + ccol;
            const float bb = ffb[gcol];
#pragma unroll
            for (int j = 0; j < 4; ++j) {
                const int grow = r0 + w * 16 + crow0 + j;
                Fb[(size_t)grow * 64 + gcol] = f2bf(fmaxf(accF[n][j] + bb, 0.f));
            }
        }
    }

    if constexpr (CKV) {
        // 4 chunks of 64 output cols; out[64 rows][64 cols], K=128 per chunk.
        for (int cc = 0; cc < 4; ++cc) {
            __syncthreads();   // y visible (cc=0) / previous chunk reads done
            for (int i = t; i < 1024; i += 256) {
                const int row = i >> 4, ch = i & 15;
                *(short8*)((char*)ckvWs + row * 256 + ((ch * 16) ^ ((row & 7) << 4))) =
                    *(const short8*)(ckvW + (size_t)(cc * 64 + row) * 128 + ch * 8);
            }
            __syncthreads();
            f32x4 accC[4];
#pragma unroll
            for (int n = 0; n < 4; ++n) accC[n] = (f32x4)0.f;
#pragma unroll
            for (int ks = 0; ks < 4; ++ks) {
                const int arow2 = w * 16 + lrow;
                const int acol = (ks * 64 + lk * 16) ^ ((arow2 & 7) << 4);
                const bf16x8 af = *(const bf16x8*)((const char*)Ws + arow2 * 256 + acol);
#pragma unroll
                for (int n = 0; n < 4; ++n) {
                    const int brow = n * 16 + lrow;
                    const int bcol = (ks * 64 + lk * 16) ^ ((brow & 7) << 4);
                    const bf16x8 bf = *(const bf16x8*)((const char*)ckvWs + brow * 256 + bcol);
                    accC[n] = __builtin_amdgcn_mfma_f32_16x16x32_bf16(af, bf, accC[n], 0, 0, 0);
                }
            }
#pragma unroll
            for (int n = 0; n < 4; ++n) {
                const int gcol = cc * 64 + n * 16 + ccol;
                const float bb = ckvB[gcol];
#pragma unroll
                for (int j = 0; j < 4; ++j) {
                    const int grow = r0 + w * 16 + crow0 + j;
                    KVb[(size_t)grow * 256 + gcol] = f2bf(accC[n][j] + bb);
                }
            }
        }
    }
}

// ---------------------------------------------------------------------------
// MFMA flash attention, encoder self-attn (verified r3).
// ---------------------------------------------------------------------------
__global__ __launch_bounds__(256) void k_attn_mfma(
    const ushort* __restrict__ qkv, ushort* __restrict__ ob, float scale)
{
    __shared__ ushort Ks[208 * 40];
    __shared__ ushort Vt[32 * 232];
    __shared__ ushort Ps[4][16 * 232];
    const int bh = blockIdx.x;
    const int b = bh >> 2, h = bh & 3;
    const int t = threadIdx.x, w = t >> 6, l = t & 63;
    const int lr = l & 15, lg = l >> 4;

    for (int idx = t; idx < 784; idx += 256) {
        const int j = idx >> 2, ch = idx & 3;
        const size_t base = ((size_t)j * 256 + b) * 384 + h * 32 + ch * 8;
        *(short8*)(Ks + j * 40 + ch * 8) = *(const short8*)(qkv + base + 128);
        short8 v = *(const short8*)(qkv + base + 256);
#pragma unroll
        for (int q = 0; q < 8; ++q)
            Vt[(ch * 8 + q) * 232 + j] = (ushort)v[q];
    }
    for (int idx = t; idx < 32 * 36; idx += 256)
        Vt[(idx / 36) * 232 + 196 + (idx % 36)] = 0;
    for (int i = l; i < 256; i += 64)
        Ps[w][(i >> 4) * 232 + 208 + (i & 15)] = 0;
    __syncthreads();

    for (int qt = w; qt < 13; qt += 4) {
        int qr = qt * 16 + lr; if (qr > 195) qr = 195;
        const bf16x8 qf = *(const bf16x8*)(qkv + ((size_t)qr * 256 + b) * 384 + h * 32 + lg * 8);

        f32x4 s[13];
#pragma unroll
        for (int jn = 0; jn < 13; ++jn) {
            const bf16x8 kf = *(const bf16x8*)(Ks + (jn * 16 + lr) * 40 + lg * 8);
            s[jn] = __builtin_amdgcn_mfma_f32_16x16x32_bf16(qf, kf, (f32x4)0.f, 0, 0, 0);
        }
        if (lr >= 4) {
            s[12][0] = -3.0e38f; s[12][1] = -3.0e38f;
            s[12][2] = -3.0e38f; s[12][3] = -3.0e38f;
        }

        float inv[4];
        ushort* pw = Ps[w];
#pragma unroll
        for (int j = 0; j < 4; ++j) {
            float m = s[0][j];
#pragma unroll
            for (int jn = 1; jn < 13; ++jn) m = fmaxf(m, s[jn][j]);
            m = fmaxf(m, __shfl_xor(m, 1, 64));
            m = fmaxf(m, __shfl_xor(m, 2, 64));
            m = fmaxf(m, __shfl_xor(m, 4, 64));
            m = fmaxf(m, __shfl_xor(m, 8, 64));
            float sum = 0.f;
#pragma unroll
            for (int jn = 0; jn < 13; ++jn) {
                const float p = __expf((s[jn][j] - m) * scale);
                s[jn][j] = p;
                sum += p;
            }
            sum += __shfl_xor(sum, 1, 64);
            sum += __shfl_xor(sum, 2, 64);
            sum += __shfl_xor(sum, 4, 64);
            sum += __shfl_xor(sum, 8, 64);
            inv[j] = 1.0f / sum;
        }
#pragma unroll
        for (int jn = 0; jn < 13; ++jn)
#pragma unroll
            for (int j = 0; j < 4; ++j)
                pw[(lg * 4 + j) * 232 + jn * 16 + lr] = f2bf(s[jn][j]);

        f32x4 o0 = (f32x4)0.f, o1 = (f32x4)0.f;
#pragma unroll
        for (int kt = 0; kt < 7; ++kt) {
            const bf16x8 pf = *(const bf16x8*)(pw + lr * 232 + kt * 32 + lg * 8);
            const bf16x8 v0 = *(const bf16x8*)(Vt + lr * 232 + kt * 32 + lg * 8);
            const bf16x8 v1 = *(const bf16x8*)(Vt + (16 + lr) * 232 + kt * 32 + lg * 8);
            o0 = __builtin_amdgcn_mfma_f32_16x16x32_bf16(pf, v0, o0, 0, 0, 0);
            o1 = __builtin_amdgcn_mfma_f32_16x16x32_bf16(pf, v1, o1, 0, 0, 0);
        }
#pragma unroll
        for (int j = 0; j < 4; ++j) {
            const int r = qt * 16 + lg * 4 + j;
            if (r < 196) {
                const size_t o = ((size_t)r * 256 + b) * 128 + h * 32;
                ob[o + lr]      = f2bf(o0[j] * inv[j]);
                ob[o + 16 + lr] = f2bf(o1[j] * inv[j]);
            }
        }
    }
}

// ---------------------------------------------------------------------------
// Fused attention (decoder cross path; f32 math, KV stored bf16 this round).
// ---------------------------------------------------------------------------
__global__ __launch_bounds__(256) void k_attn(
    const float* __restrict__ qp, int qstride,
    const ushort* __restrict__ kvp, int kvstride, int koff, int voff,
    float* __restrict__ op, ushort* __restrict__ ob,
    int Lq, int Lk, float scale)
{
    __shared__ float Kl[196 * 36];
    __shared__ float Vl[196 * 32];
    __shared__ float pbuf[4][256];
    const int bh = blockIdx.x;
    const int b = bh >> 2;
    const int h = bh & 3;
    const int t = threadIdx.x;
    const int w = t >> 6;
    const int l = t & 63;

    for (int idx = t; idx < Lk * 8; idx += 256) {
        const int j = idx >> 3;
        const int kq = idx & 7;
        const size_t row = ((size_t)j * 256 + b) * kvstride + h * 32 + kq * 4;
        const ushort4 k4 = *(const ushort4*)(kvp + row + koff);
        const ushort4 v4 = *(const ushort4*)(kvp + row + voff);
        Kl[j * 36 + kq * 4 + 0] = bf2f(k4.x);
        Kl[j * 36 + kq * 4 + 1] = bf2f(k4.y);
        Kl[j * 36 + kq * 4 + 2] = bf2f(k4.z);
        Kl[j * 36 + kq * 4 + 3] = bf2f(k4.w);
        Vl[j * 32 + kq * 4 + 0] = bf2f(v4.x);
        Vl[j * 32 + kq * 4 + 1] = bf2f(v4.y);
        Vl[j * 32 + kq * 4 + 2] = bf2f(v4.z);
        Vl[j * 32 + kq * 4 + 3] = bf2f(v4.w);
    }
    if ((Lk & 1) && t < 8) *(float4*)(&Vl[Lk * 32 + t * 4]) = make_float4(0.f, 0.f, 0.f, 0.f);
    __syncthreads();

    const int Lh = (Lk + 1) >> 1;
    const int half = l >> 5;
    const int kk = l & 31;
    const int jb = half * Lh;

    for (int jq = w; jq < Lq; jq += 4) {
        const float* qrow = qp + ((size_t)jq * 256 + b) * qstride + h * 32;
        float4 q4[8];
#pragma unroll
        for (int kq = 0; kq < 8; ++kq) q4[kq] = *(const float4*)(qrow + kq * 4);

        float s[4];
#pragma unroll
        for (int r = 0; r < 4; ++r) {
            const int j = l + (r << 6);
            float acc = -3.0e38f;
            if (j < Lk) {
                acc = 0.f;
#pragma unroll
                for (int kq = 0; kq < 8; ++kq) {
                    const float4 kv = *(const float4*)(&Kl[j * 36 + kq * 4]);
                    acc += q4[kq].x * kv.x + q4[kq].y * kv.y +
                           q4[kq].z * kv.z + q4[kq].w * kv.w;
                }
                acc *= scale;
            }
            s[r] = acc;
        }
        float m = fmaxf(fmaxf(s[0], s[1]), fmaxf(s[2], s[3]));
        m = wred_max(m);
        float sum = 0.f;
#pragma unroll
        for (int r = 0; r < 4; ++r) {
            const int j = l + (r << 6);
            float p = __expf(s[r] - m);
            if (j >= Lk) p = 0.f;
            pbuf[w][j] = p;
            sum += p;
        }
        sum = wred_sum(sum);
        const float inv = 1.0f / sum;
        __threadfence_block();

        float o = 0.f;
        for (int jj = 0; jj < Lh; ++jj) {
            const float pv = pbuf[w][jb + jj];
            const float vv = Vl[(jb + jj) * 32 + kk];
            o += pv * vv;
        }
        o += __shfl_xor(o, 32, 64);
        o *= inv;
        if (l < 32) {
            const size_t oi = ((size_t)jq * 256 + b) * 128 + h * 32 + l;
            if (op) op[oi] = o;
            if (ob) ob[oi] = f2bf(o);
        }
        __threadfence_block();
    }
}

// ---------------------------------------------------------------------------
// Fused decoder part 2 v3 (verified r9) + L2 weight prefetch (r17).
// ---------------------------------------------------------------------------
__global__ __launch_bounds__(512) void k_dec2(
    const float* __restrict__ TGo, const float* __restrict__ AT,
    const float* __restrict__ caoW, const float* __restrict__ caob,
    const float* __restrict__ ln2s, const float* __restrict__ ln2b,
    const float* __restrict__ ff1W, const float* __restrict__ ff1b,
    const float* __restrict__ ff2W, const float* __restrict__ ff2b,
    const float* __restrict__ ln3s, const float* __restrict__ ln3b,
    const float* __restrict__ ns, const float* __restrict__ nb,
    const float* __restrict__ l1W, const float* __restrict__ l1b,
    const float* __restrict__ l2w, const float* __restrict__ l2b,
    float* __restrict__ qout)
{
    __shared__ float tg[15][128], ao[15][128], o2[15][128];
    __shared__ float ff[15][64];
    const int b = blockIdx.x, t = threadIdx.x;
    const int w = t >> 6, l = t & 63;

    {
        float pf = 0.f;
#define PFW(P, N) for (int i = t * 32; i < (N); i += 512 * 32) pf += P[i];
        PFW(caoW, 128 * 128)
        PFW(ff1W, 128 * 64)
        PFW(ff2W, 64 * 128)
        PFW(l1W, 128 * 128)
#undef PFW
        asm volatile("" :: "v"(pf));
    }

    for (int idx = t; idx < 1920; idx += 512) {
        const int r = idx >> 7, c = idx & 127;
        tg[r][c] = TGo[((size_t)r * 256 + b) * 128 + c];
        ao[r][c] = AT[((size_t)r * 256 + b) * 128 + c];
    }
    __syncthreads();

    {
        const int c = t & 127, g = t >> 7;
        const int r3 = (g + 12 < 15) ? g + 12 : 0;
        float a0 = 0.f, a1 = 0.f, a2 = 0.f, a3 = 0.f;
#pragma unroll 4
        for (int k = 0; k < 128; ++k) {
            const float wv = caoW[(size_t)k * 128 + c];
            a0 += ao[g][k] * wv;
            a1 += ao[g + 4][k] * wv;
            a2 += ao[g + 8][k] * wv;
            a3 += ao[r3][k] * wv;
        }
        const float bb = caob[c];
        o2[g][c]     = a0 + bb + tg[g][c];
        o2[g + 4][c] = a1 + bb + tg[g + 4][c];
        o2[g + 8][c] = a2 + bb + tg[g + 8][c];
        if (g + 12 < 15) o2[g + 12][c] = a3 + bb + tg[g + 12][c];
    }
    __syncthreads();
    for (int r = w; r < 15; r += 8) {
        const float x0 = o2[r][l], x1 = o2[r][l + 64];
        const float sm = wred_sum(x0 + x1);
        const float sq = wred_sum(x0 * x0 + x1 * x1);
        const float mean = sm * 0.0078125f;
        const float rstd = rsqrtf(sq * 0.0078125f - mean * mean + 1e-5f);
        tg[r][l]      = (x0 - mean) * rstd * ln2s[l] + ln2b[l];
        tg[r][l + 64] = (x1 - mean) * rstd * ln2s[l + 64] + ln2b[l + 64];
    }
    __syncthreads();
    {
        const int n = t & 63, g = t >> 6;
        const int r1 = (g + 8 < 15) ? g + 8 : 0;
        float a0 = 0.f, a1 = 0.f;
#pragma unroll 4
        for (int k = 0; k < 128; ++k) {
            const float wv = ff1W[(size_t)k * 64 + n];
            a0 += tg[g][k] * wv;
            a1 += tg[r1][k] * wv;
        }
        const float bb = ff1b[n];
        ff[g][n] = fmaxf(a0 + bb, 0.f);
        if (g + 8 < 15) ff[g + 8][n] = fmaxf(a1 + bb, 0.f);
    }
    __syncthreads();
    {
        const int c = t & 127, g = t >> 7;
        const int r3 = (g + 12 < 15) ? g + 12 : 0;
        float a0 = 0.f, a1 = 0.f, a2 = 0.f, a3 = 0.f;
#pragma unroll 4
        for (int k = 0; k < 64; ++k) {
            const float wv = ff2W[(size_t)k * 128 + c];
            a0 += ff[g][k] * wv;
            a1 += ff[g + 4][k] * wv;
            a2 += ff[g + 8][k] * wv;
            a3 += ff[r3][k] * wv;
        }
        const float bb = ff2b[c];
        o2[g][c]     = a0 + bb + tg[g][c];
        o2[g + 4][c] = a1 + bb + tg[g + 4][c];
        o2[g + 8][c] = a2 + bb + tg[g + 8][c];
        if (g + 12 < 15) o2[g + 12][c] = a3 + bb + tg[g + 12][c];
    }
    __syncthreads();
    for (int r = w; r < 15; r += 8) {
        const float x0 = o2[r][l], x1 = o2[r][l + 64];
        const float sm = wred_sum(x0 + x1);
        const float sq = wred_sum(x0 * x0 + x1 * x1);
        const float mean = sm * 0.0078125f;
        const float rstd = rsqrtf(sq * 0.0078125f - mean * mean + 1e-5f);
        const float y0 = (x0 - mean) * rstd * ln3s[l] + ln3b[l];
        const float y1 = (x1 - mean) * rstd * ln3s[l + 64] + ln3b[l + 64];
        const float sm2 = wred_sum(y0 + y1);
        const float sq2 = wred_sum(y0 * y0 + y1 * y1);
        const float mean2 = sm2 * 0.0078125f;
        const float rstd2 = rsqrtf(sq2 * 0.0078125f - mean2 * mean2 + 1e-5f);
        tg[r][l]      = (y0 - mean2) * rstd2 * ns[l] + nb[l];
        tg[r][l + 64] = (y1 - mean2) * rstd2 * ns[l + 64] + nb[l + 64];
    }
    __syncthreads();
    {
        const int c = t & 127, g = t >> 7;
        const int r3 = (g + 12 < 15) ? g + 12 : 0;
        float a0 = 0.f, a1 = 0.f, a2 = 0.f, a3 = 0.f;
#pragma unroll 4
        for (int k = 0; k < 128; ++k) {
            const float wv = l1W[(size_t)k * 128 + c];
            a0 += tg[g][k] * wv;
            a1 += tg[g + 4][k] * wv;
            a2 += tg[g + 8][k] * wv;
            a3 += tg[r3][k] * wv;
        }
        const float bb = l1b[c];
        o2[g][c]     = fmaxf(a0 + bb, 0.f);
        o2[g + 4][c] = fmaxf(a1 + bb, 0.f);
        o2[g + 8][c] = fmaxf(a2 + bb, 0.f);
        if (g + 12 < 15) o2[g + 12][c] = fmaxf(a3 + bb, 0.f);
    }
    __syncthreads();
    for (int r = w; r < 15; r += 8) {
        const float d = wred_sum(o2[r][l] * l2w[l] + o2[r][l + 64] * l2w[l + 64]);
        if (l == 0) qout[b * 15 + r] = d + l2b[0];
    }
}

// ---------------------------------------------------------------------------
extern "C" void kernel_launch(void* const* d_in, const int* in_sizes, int n_in,
                              void* d_out, int out_size, void* d_ws, size_t ws_size,
                              hipStream_t stream)
{
    (void)in_sizes; (void)n_in; (void)out_size; (void)ws_size;
    const float* image      = (const float*)d_in[0];
    const float* angle      = (const float*)d_in[1];
    const float* pos_x      = (const float*)d_in[2];
    const float* pos_y      = (const float*)d_in[3];
    const float* sk         = (const float*)d_in[4];
    const float* patch_W    = (const float*)d_in[5];
    const float* patch_b    = (const float*)d_in[6];
    const float* pos_emb    = (const float*)d_in[7];
    const float* enc_qkv_W  = (const float*)d_in[8];
    const float* enc_qkv_b  = (const float*)d_in[9];
    const float* enc_out_W  = (const float*)d_in[10];
    const float* enc_out_b  = (const float*)d_in[11];
    const float* enc_ln1_s  = (const float*)d_in[12];
    const float* enc_ln1_b  = (const float*)d_in[13];
    const float* enc_ff1_W  = (const float*)d_in[14];
    const float* enc_ff1_b  = (const float*)d_in[15];
    const float* enc_ff2_W  = (const float*)d_in[16];
    const float* enc_ff2_b  = (const float*)d_in[17];
    const float* enc_ln2_s  = (const float*)d_in[18];
    const float* enc_ln2_b  = (const float*)d_in[19];
    const float* dec_sa_qkv_W = (const float*)d_in[20];
    const float* dec_sa_qkv_b = (const float*)d_in[21];
    const float* dec_sa_out_W = (const float*)d_in[22];
    const float* dec_sa_out_b = (const float*)d_in[23];
    const float* dec_ca_qkv_W = (const float*)d_in[24];
    const float* dec_ca_qkv_b = (const float*)d_in[25];
    const float* dec_ca_out_W = (const float*)d_in[26];
    const float* dec_ca_out_b = (const float*)d_in[27];
    const float* dec_ln1_s  = (const float*)d_in[28];
    const float* dec_ln1_b  = (const float*)d_in[29];
    const float* dec_ln2_s  = (const float*)d_in[30];
    const float* dec_ln2_b  = (const float*)d_in[31];
    const float* dec_ln3_s  = (const float*)d_in[32];
    const float* dec_ln3_b  = (const float*)d_in[33];
    const float* dec_ff1_W  = (const float*)d_in[34];
    const float* dec_ff1_b  = (const float*)d_in[35];
    const float* dec_ff2_W  = (const float*)d_in[36];
    const float* dec_ff2_b  = (const float*)d_in[37];
    const float* dec_norm_s = (const float*)d_in[38];
    const float* dec_norm_b = (const float*)d_in[39];
    const float* sk1_W = (const float*)d_in[40];
    const float* sk1_b = (const float*)d_in[41];
    const float* sk2_W = (const float*)d_in[42];
    const float* sk2_b = (const float*)d_in[43];
    const float* sk3_W = (const float*)d_in[44];
    const float* sk3_b = (const float*)d_in[45];
    const float* act_W = (const float*)d_in[46];
    const float* act_b = (const float*)d_in[47];
    const float* l1_W  = (const float*)d_in[48];
    const float* l1_b  = (const float*)d_in[49];
    const float* l2_W  = (const float*)d_in[50];
    const float* l2_b  = (const float*)d_in[51];

    // Workspace (float offsets)
    float* ws = (float*)d_ws;
    float* S0   = ws;               // src f32 residual stream  [6,422,528]
    float* QKVr = ws + 6422528;     // big overlay region       [19,267,584]
    float* T0   = ws + 25690112;    // decoder cross-attn out   [6,422,528]
    float* T1   = ws + 32112640;    // (spare)                  [6,422,528]
    float* F1   = ws + 38535168;    // F1b bf16                 [3,211,264]
    float* M0r  = ws + 41746432;    // T0b bf16                 [6,422,528]
    float* S1s  = ws + 48168960;
    float* TG   = S1s + 156672;     // tgt f32 15*256*128
    ushort* WTS = (ushort*)(ws + 48817152);

    // Overlays
    ushort* QKVb = (ushort*)QKVr;            // enc QKV bf16 [50176][384]
    ushort* KVb  = (ushort*)QKVr;            // cross K/V bf16 [50176][256] (disjoint lifetime)
    float* DQ   = QKVr + 14319616;           // dec cross Q f32
    float* DT0  = T0;
    ushort* T0b  = (ushort*)M0r;
    ushort* F1b  = (ushort*)F1;
    ushort* wt_patch = WTS;
    ushort* wt_qkv   = WTS + 98304;
    ushort* wt_out   = WTS + 147456;
    ushort* wt_ff1   = WTS + 163840;
    ushort* wt_ff2   = WTS + 172032;
    ushort* wt_ckv   = WTS + 180224;
    (void)T1;

    const float rs = 0.17677669529663687f;  // 1/sqrt(32)

    // ---- prep ----
    k_wconv<<<dim3(832), 256, 0, stream>>>(patch_W, enc_qkv_W, enc_out_W,
                                           enc_ff1_W, enc_ff2_W, dec_ca_qkv_W, WTS);

    // ---- merged dec1 + patchify-GEMM + fused QKV (r19-verbatim) ----
    k_pg_dec1<<<dim3(1040), 512, 49152, stream>>>(
        image, wt_patch, patch_b, pos_emb, S0,
        wt_qkv, enc_qkv_b, QKVb,
        sk, sk1_W, sk1_b, sk2_W, sk2_b, sk3_W, sk3_b,
        angle, pos_x, pos_y, act_W, act_b,
        dec_sa_qkv_W, dec_sa_qkv_b, dec_sa_out_W, dec_sa_out_b,
        dec_ln1_s, dec_ln1_b, dec_ca_qkv_W, dec_ca_qkv_b, TG, DQ);

    // ---- encoder ----
    k_attn_mfma<<<dim3(1024), 256, 0, stream>>>(QKVb, T0b, rs);
    k_gemm_ln<1, 0><<<dim3(784), 256, 0, stream>>>(           // out-proj + LN1 + FF1
        T0b, 128, wt_out, 128, enc_out_b, S0, enc_ln1_s, enc_ln1_b, S0, nullptr,
        wt_ff1, enc_ff1_b, F1b, nullptr, nullptr, nullptr);
    k_gemm_ln<0, 1><<<dim3(784), 256, 0, stream>>>(           // FF2 + LN2 + cross-KV(bf16)
        F1b, 64, wt_ff2, 64, enc_ff2_b, S0, enc_ln2_s, enc_ln2_b, nullptr, nullptr,
        nullptr, nullptr, nullptr, wt_ckv, dec_ca_qkv_b + 128, KVb);

    // ---- decoder cross-attn + tail ----
    k_attn<<<dim3(1024), 256, 0, stream>>>(DQ, 128, KVb, 256, 0, 128,
                                           DT0, nullptr, 15, 196, rs);
    k_dec2<<<dim3(256), 512, 0, stream>>>(
        TG, DT0, dec_ca_out_W, dec_ca_out_b, dec_ln2_s, dec_ln2_b,
        dec_ff1_W, dec_ff1_b, dec_ff2_W, dec_ff2_b,
        dec_ln3_s, dec_ln3_b, dec_norm_s, dec_norm_b,
        l1_W, l1_b, l2_W, l2_b, (float*)d_out);
}

// Round 23
// 276.869 us; speedup vs baseline: 1.0235x; 1.0056x over previous
//
#include <hip/hip_runtime.h>
#include <math.h>

#define BSZ 256
#define DIM 128
#define NHD 4
#define NPATCH 196
#define NACT 15

typedef float f32x4 __attribute__((ext_vector_type(4)));
typedef __bf16 bf16x8 __attribute__((ext_vector_type(8)));
typedef short short8 __attribute__((ext_vector_type(8)));

__device__ __forceinline__ float wred_sum(float v) {
#pragma unroll
    for (int m = 1; m < 64; m <<= 1) v += __shfl_xor(v, m, 64);
    return v;
}
__device__ __forceinline__ float wred_max(float v) {
#pragma unroll
    for (int m = 1; m < 64; m <<= 1) v = fmaxf(v, __shfl_xor(v, m, 64));
    return v;
}
__device__ __forceinline__ ushort f2bf(float f) {  // RNE bf16
    unsigned u = __float_as_uint(f);
    return (ushort)((u + 0x7fffu + ((u >> 16) & 1u)) >> 16);
}
__device__ __forceinline__ float bf2f(ushort u) {
    return __uint_as_float((unsigned)u << 16);
}

// ---------------------------------------------------------------------------
// Weight convert+transpose to bf16 [N][K] (patch K-permuted), packed.
// ---------------------------------------------------------------------------
__global__ __launch_bounds__(256) void k_wconv(
    const float* __restrict__ pW, const float* __restrict__ qkvW,
    const float* __restrict__ outW, const float* __restrict__ ff1W,
    const float* __restrict__ ff2W, const float* __restrict__ ckvW,
    ushort* __restrict__ o)
{
    int i = blockIdx.x * 256 + threadIdx.x;
    if (i < 98304) {
        int n = i / 768, kp = i % 768;
        int c = kp >> 8, q = kp & 255;
        o[i] = f2bf(pW[(q * 3 + c) * 128 + n]); return;
    }
    i -= 98304;
    if (i < 49152) { int n = i >> 7, k = i & 127; o[98304 + i] = f2bf(qkvW[k * 384 + n]); return; }
    i -= 49152;
    if (i < 16384) { int n = i >> 7, k = i & 127; o[147456 + i] = f2bf(outW[k * 128 + n]); return; }
    i -= 16384;
    if (i < 8192)  { int n = i >> 7, k = i & 127; o[163840 + i] = f2bf(ff1W[k * 64 + n]); return; }
    i -= 8192;
    if (i < 8192)  { int n = i >> 6, k = i & 63;  o[172032 + i] = f2bf(ff2W[k * 128 + n]); return; }
    i -= 8192;
    if (i < 32768) { int n = i >> 7, k = i & 127; o[180224 + i] = f2bf(ckvW[k * 384 + 128 + n]); return; }
}

// ---------------------------------------------------------------------------
// MERGED kernel (verified r18/r19): blocks [0,256) = dec1 (L2 prefetch);
// blocks [256,1040) = patchify-GEMM + fused encoder-QKV stage.
// This round: src residual written as bf16 (storage-only change).
// ---------------------------------------------------------------------------
__global__ __launch_bounds__(512) void k_pg_dec1(
    const float* __restrict__ img, const ushort* __restrict__ Wt,
    const float* __restrict__ pbias, const float* __restrict__ pe,
    ushort* __restrict__ Cbsrc,
    const ushort* __restrict__ qkvWt, const float* __restrict__ qkvB,
    ushort* __restrict__ QKVb,
    const float* __restrict__ sk,
    const float* __restrict__ W1, const float* __restrict__ b1,
    const float* __restrict__ W2, const float* __restrict__ b2,
    const float* __restrict__ W3, const float* __restrict__ b3,
    const float* __restrict__ ang, const float* __restrict__ px,
    const float* __restrict__ py,
    const float* __restrict__ actW, const float* __restrict__ actb,
    const float* __restrict__ saW, const float* __restrict__ sab,
    const float* __restrict__ saoW, const float* __restrict__ saob,
    const float* __restrict__ ln1s, const float* __restrict__ ln1b,
    const float* __restrict__ caW, const float* __restrict__ cab,
    float* __restrict__ TGo, float* __restrict__ DQ)
{
    extern __shared__ char smem[];
    const int t = threadIdx.x;
    const int w = t >> 6, l = t & 63;

    if (blockIdx.x >= 256) {
        ushort* As = (ushort*)smem;          // 16 KB (2 x 64x64)
        ushort* Ws = As + 2 * 64 * 64;       // 32 KB (2 x 128x64)
        const bool act = t < 256;
        const int pb = blockIdx.x - 256;
        const int p = pb >> 2, bq = pb & 3;
        const int hp_ = p / 14, wp = p % 14;
        const int r0 = p * 256 + bq * 64;
        const int wm = w >> 1, wn = w & 1;
        const int lrow = l & 15, lk = l >> 4;
        const int arow = (t & 255) >> 2;
        const int b_img = bq * 64 + arow;
        const float* gimg = img + (size_t)b_img * 150528 + hp_ * 3584 + wp * 16;

        f32x4 acc[2][4];
#pragma unroll
        for (int m = 0; m < 2; ++m)
#pragma unroll
            for (int n = 0; n < 4; ++n) acc[m][n] = (f32x4)0.f;

        float4 va[4];
        short8 wr[4];

        auto loadT = [&](int kc) {
            if (!act) return;
            const int c = kc >> 8, p1q = (kc >> 6) & 3;
            const float* gc = gimg + c * 50176 + p1q * 896;
#pragma unroll
            for (int i = 0; i < 4; ++i)
                va[i] = *(const float4*)(gc + i * 224 + (t & 3) * 4);
#pragma unroll
            for (int j = 0; j < 4; ++j) {
                const int i2 = t + 256 * j;
                const int row = i2 >> 3, ch = i2 & 7;
                wr[j] = *(const short8*)(Wt + (size_t)row * 768 + kc + ch * 8);
            }
        };
        auto storeT = [&](int buf) {
            if (!act) return;
            ushort* Ab = As + buf * 64 * 64;
            ushort* Wb = Ws + buf * 128 * 64;
#pragma unroll
            for (int i = 0; i < 4; ++i) {
                ushort4 o4;
                o4.x = f2bf(va[i].x); o4.y = f2bf(va[i].y);
                o4.z = f2bf(va[i].z); o4.w = f2bf(va[i].w);
                const int kq = (t & 3) + 4 * i;
                const int bo = (kq * 8) ^ ((arow & 7) << 4);
                *(ushort4*)((char*)Ab + arow * 128 + bo) = o4;
            }
#pragma unroll
            for (int j = 0; j < 4; ++j) {
                const int i2 = t + 256 * j;
                const int row = i2 >> 3, ch = i2 & 7;
                const int sw = (ch * 16) ^ ((row & 7) << 4);
                *(short8*)((char*)Wb + row * 128 + sw) = wr[j];
            }
        };
        auto mfmaT = [&](int buf) {
            if (!act) return;
            const ushort* Ab = As + buf * 64 * 64;
            const ushort* Wb = Ws + buf * 128 * 64;
#pragma unroll
            for (int ks = 0; ks < 2; ++ks) {
                bf16x8 af[2], bfr[4];
#pragma unroll
                for (int m = 0; m < 2; ++m) {
                    const int row = wm * 32 + m * 16 + lrow;
                    const int col = (ks * 64 + lk * 16) ^ ((row & 7) << 4);
                    af[m] = *(const bf16x8*)((const char*)Ab + row * 128 + col);
                }
#pragma unroll
                for (int n = 0; n < 4; ++n) {
                    const int row = wn * 64 + n * 16 + lrow;
                    const int col = (ks * 64 + lk * 16) ^ ((row & 7) << 4);
                    bfr[n] = *(const bf16x8*)((const char*)Wb + row * 128 + col);
                }
#pragma unroll
                for (int m = 0; m < 2; ++m)
#pragma unroll
                    for (int n = 0; n < 4; ++n)
                        acc[m][n] = __builtin_amdgcn_mfma_f32_16x16x32_bf16(
                            af[m], bfr[n], acc[m][n], 0, 0, 0);
            }
        };

        loadT(0);
        for (int it = 0; it < 12; it += 2) {
            storeT(0);
            if (it + 1 < 12) loadT((it + 1) * 64);
            __syncthreads();
            mfmaT(0);
            storeT(1);
            if (it + 2 < 12) loadT((it + 2) * 64);
            __syncthreads();
            mfmaT(1);
        }

        __syncthreads();
        const int crow0 = (l >> 4) * 4;
        const int ccol = l & 15;
        if (act) {
#pragma unroll
            for (int m = 0; m < 2; ++m) {
                const int rowb = wm * 32 + m * 16 + crow0;
#pragma unroll
                for (int n = 0; n < 4; ++n) {
                    const int col = wn * 64 + n * 16 + ccol;
                    const float bv = pbias[col] + pe[p * 128 + col];
#pragma unroll
                    for (int j = 0; j < 4; ++j) {
                        const int row = rowb + j;
                        const float v = acc[m][n][j] + bv;
                        const ushort vb = f2bf(v);
                        Cbsrc[(size_t)(r0 + row) * 128 + col] = vb;
                        const int bo = row * 256 + (((col >> 3) * 16) ^ ((row & 7) << 4)) + (col & 7) * 2;
                        *(ushort*)((char*)As + bo) = vb;
                    }
                }
            }
        }

        // ---- fused QKV stage (verified r18) ----
        const int wm2 = w >> 1;
        const int wn2 = w & 1;
        for (int cc = 0; cc < 3; ++cc) {
            __syncthreads();
            for (int i = t; i < 2048; i += 512) {
                const int row = i >> 4, ch = i & 15;
                *(short8*)((char*)Ws + row * 256 + ((ch * 16) ^ ((row & 7) << 4))) =
                    *(const short8*)(qkvWt + (size_t)(cc * 128 + row) * 128 + ch * 8);
            }
            __syncthreads();
            f32x4 a2[4];
#pragma unroll
            for (int n = 0; n < 4; ++n) a2[n] = (f32x4)0.f;
#pragma unroll
            for (int ks = 0; ks < 4; ++ks) {
                const int arow2 = wm2 * 16 + lrow;
                const int acol = (ks * 64 + lk * 16) ^ ((arow2 & 7) << 4);
                const bf16x8 af = *(const bf16x8*)((const char*)As + arow2 * 256 + acol);
#pragma unroll
                for (int n = 0; n < 4; ++n) {
                    const int brow = wn2 * 64 + n * 16 + lrow;
                    const int bcol = (ks * 64 + lk * 16) ^ ((brow & 7) << 4);
                    const bf16x8 bf = *(const bf16x8*)((const char*)Ws + brow * 256 + bcol);
                    a2[n] = __builtin_amdgcn_mfma_f32_16x16x32_bf16(af, bf, a2[n], 0, 0, 0);
                }
            }
#pragma unroll
            for (int n = 0; n < 4; ++n) {
                const int gcol = cc * 128 + wn2 * 64 + n * 16 + ccol;
                const float bb = qkvB[gcol];
#pragma unroll
                for (int j = 0; j < 4; ++j) {
                    const int grow = r0 + wm2 * 16 + crow0 + j;
                    QKVb[(size_t)grow * 384 + gcol] = f2bf(a2[n][j] + bb);
                }
            }
        }
        return;
    }

    // ================= dec1 body (r17-verbatim, incl. L2 prefetch) ==========
    float* tg  = (float*)smem;
    float* qkv = tg + 1920;
    float* ao  = qkv + 5820;
    float* xr  = ao + 1920;
    float* h1  = xr + 256;
    float* h2  = h1 + 256;
    float* s3  = h2 + 256;
    float* pbv = s3 + 100;
    float* hp  = pbv + 64;
    const int b = blockIdx.x;

    {
        float pf = 0.f;
#define PFW(P, N) for (int i = t * 32; i < (N); i += 512 * 32) pf += P[i];
        PFW(W1, 200 * 256)
        PFW(W2, 256 * 256)
        PFW(W3, 256 * 100)
        PFW(actW, 118 * 128)
        PFW(saW, 128 * 384)
        PFW(saoW, 128 * 128)
        PFW(caW, 128 * 384)
#undef PFW
        asm volatile("" :: "v"(pf));
    }

    if (t < 256) xr[t] = (t < 200) ? sk[(size_t)b * 200 + t] : 0.f;
    __syncthreads();
    {
        const int c = t & 255, g = t >> 8;
        const int k0 = g * 100;
        float a = 0.f;
#pragma unroll 10
        for (int k = k0; k < k0 + 100; ++k) a += xr[k] * W1[k * 256 + c];
        hp[g * 256 + c] = a;
    }
    __syncthreads();
    if (t < 256) h1[t] = fmaxf(hp[t] + hp[256 + t] + b1[t], 0.f);
    __syncthreads();
    {
        const int c = t & 255, g = t >> 8;
        const int k0 = g * 128;
        float a = 0.f;
#pragma unroll 8
        for (int k = k0; k < k0 + 128; ++k) a += h1[k] * W2[k * 256 + c];
        hp[g * 256 + c] = a;
    }
    __syncthreads();
    if (t < 256) h2[t] = fmaxf(hp[t] + hp[256 + t] + b2[t], 0.f);
    __syncthreads();
    if (t < 400) {
        const int c = t % 100, g = t / 100;
        const int k0 = g * 64;
        float a = 0.f;
#pragma unroll 8
        for (int k = k0; k < k0 + 64; ++k) a += h2[k] * W3[k * 100 + c];
        hp[g * 256 + c] = a;
    }
    __syncthreads();
    if (t < 100) s3[t] = hp[t] + hp[256 + t] + hp[512 + t] + hp[768 + t] + b3[t];
    __syncthreads();
    {
        const int c = t & 127, g = t >> 7;
        const int k0 = g * 25;
        float a = 0.f;
#pragma unroll 5
        for (int k = k0; k < k0 + 25; ++k) a += s3[k] * actW[(18 + k) * 128 + c];
        hp[g * 256 + c] = a;
    }
    __syncthreads();
    if (t < 128) {
        const float base = actb[t] + hp[t] + hp[256 + t] + hp[512 + t] + hp[768 + t] +
                           ang[b] * actW[15 * 128 + t] + px[b] * actW[16 * 128 + t] +
                           py[b] * actW[17 * 128 + t];
#pragma unroll
        for (int i = 0; i < 15; ++i) tg[i * 128 + t] = base + actW[i * 128 + t];
    }
    __syncthreads();

    if (t < 384) {
        float acc[15];
#pragma unroll
        for (int r = 0; r < 15; ++r) acc[r] = 0.f;
#pragma unroll 4
        for (int k = 0; k < 128; ++k) {
            const float wv = saW[(size_t)k * 384 + t];
#pragma unroll
            for (int r = 0; r < 15; ++r) acc[r] += tg[r * 128 + k] * wv;
        }
        const float bb = sab[t];
#pragma unroll
        for (int r = 0; r < 15; ++r) qkv[r * 388 + t] = acc[r] + bb;
    }
    __syncthreads();

    const float rs = 0.17677669529663687f;
    if (w < 4) {
        for (int qi = 0; qi < 15; ++qi) {
            float s = -3.0e38f;
            if (l < 15) {
                s = 0.f;
#pragma unroll
                for (int d = 0; d < 32; ++d)
                    s += qkv[qi * 388 + w * 32 + d] * qkv[l * 388 + 128 + w * 32 + d];
                s *= rs;
            }
            const float m = wred_max(s);
            const float pv = (l < 15) ? __expf(s - m) : 0.f;
            const float sum = wred_sum(pv);
            if (l < 15) pbv[w * 16 + l] = pv;
            if (l < 32) {
                float o = 0.f;
#pragma unroll
                for (int j = 0; j < 15; ++j) o += pbv[w * 16 + j] * qkv[j * 388 + 256 + w * 32 + l];
                ao[qi * 128 + w * 32 + l] = o / sum;
            }
        }
    }
    __syncthreads();

    {
        const int c = t & 127, g = t >> 7;
        const int r3 = (g + 12 < 15) ? g + 12 : 0;
        float a0 = 0.f, a1 = 0.f, a2 = 0.f, a3 = 0.f;
#pragma unroll 4
        for (int k = 0; k < 128; ++k) {
            const float wv = saoW[(size_t)k * 128 + c];
            a0 += ao[g * 128 + k] * wv;
            a1 += ao[(g + 4) * 128 + k] * wv;
            a2 += ao[(g + 8) * 128 + k] * wv;
            a3 += ao[r3 * 128 + k] * wv;
        }
        const float bb = saob[c];
        qkv[g * 388 + c]       = a0 + bb + tg[g * 128 + c];
        qkv[(g + 4) * 388 + c] = a1 + bb + tg[(g + 4) * 128 + c];
        qkv[(g + 8) * 388 + c] = a2 + bb + tg[(g + 8) * 128 + c];
        if (g + 12 < 15) qkv[(g + 12) * 388 + c] = a3 + bb + tg[(g + 12) * 128 + c];
    }
    __syncthreads();
    for (int r = w; r < 15; r += 8) {
        const float x0 = qkv[r * 388 + l], x1 = qkv[r * 388 + l + 64];
        const float sm = wred_sum(x0 + x1);
        const float sq = wred_sum(x0 * x0 + x1 * x1);
        const float mean = sm * 0.0078125f;
        const float rstd = rsqrtf(sq * 0.0078125f - mean * mean + 1e-5f);
        const float y0 = (x0 - mean) * rstd * ln1s[l] + ln1b[l];
        const float y1 = (x1 - mean) * rstd * ln1s[l + 64] + ln1b[l + 64];
        tg[r * 128 + l] = y0; tg[r * 128 + l + 64] = y1;
        float* g2 = TGo + ((size_t)r * 256 + b) * 128;
        g2[l] = y0; g2[l + 64] = y1;
    }
    __syncthreads();

    {
        const int c = t & 127, g = t >> 7;
        const int r3 = (g + 12 < 15) ? g + 12 : 0;
        float a0 = 0.f, a1 = 0.f, a2 = 0.f, a3 = 0.f;
#pragma unroll 4
        for (int k = 0; k < 128; ++k) {
            const float wv = caW[(size_t)k * 384 + c];
            a0 += tg[g * 128 + k] * wv;
            a1 += tg[(g + 4) * 128 + k] * wv;
            a2 += tg[(g + 8) * 128 + k] * wv;
            a3 += tg[r3 * 128 + k] * wv;
        }
        const float bb = cab[c];
        DQ[((size_t)g * 256 + b) * 128 + c]       = a0 + bb;
        DQ[((size_t)(g + 4) * 256 + b) * 128 + c] = a1 + bb;
        DQ[((size_t)(g + 8) * 256 + b) * 128 + c] = a2 + bb;
        if (g + 12 < 15) DQ[((size_t)(g + 12) * 256 + b) * 128 + c] = a3 + bb;
    }
}

// ---------------------------------------------------------------------------
// bf16 MFMA GEMM 64x128 + residual + LayerNorm fused epilogue (verified r5);
// optional fused FF1 stage (FF=1, verified r13); optional fused cross-KV
// stage (CKV=1, verified r19/r22, KV bf16). This round: resid input is bf16.
// ---------------------------------------------------------------------------
template <int FF, int CKV>
__global__ __launch_bounds__(256) void k_gemm_ln(
    const ushort* __restrict__ A, int lda,
    const ushort* __restrict__ Wt, int K,
    const float* __restrict__ bias,
    const ushort* __restrict__ resid,
    const float* __restrict__ lns, const float* __restrict__ lnbi,
    float* __restrict__ Co, ushort* __restrict__ Cb,
    const ushort* __restrict__ ffW, const float* __restrict__ ffb,
    ushort* __restrict__ Fb,
    const ushort* __restrict__ ckvW, const float* __restrict__ ckvB,
    ushort* __restrict__ KVb)
{
    __shared__ ushort As[64 * 64];
    __shared__ ushort Ws[128 * 64];          // K-loop W tiles; later y[64][256B]
    __shared__ float psum[64][2][2];
    __shared__ ushort ffWs[FF ? 64 * 128 : 2];
    __shared__ ushort ckvWs[CKV ? 64 * 128 : 2];
    const int t = threadIdx.x;
    const int w = t >> 6, l = t & 63;
    const int r0 = blockIdx.x * 64;
    const int wm = w >> 1, wn = w & 1;
    const int lrow = l & 15, lk = l >> 4;

    f32x4 acc[2][4];
#pragma unroll
    for (int m = 0; m < 2; ++m)
#pragma unroll
        for (int n = 0; n < 4; ++n) acc[m][n] = (f32x4)0.f;

    for (int kc = 0; kc < K; kc += 64) {
        __syncthreads();
#pragma unroll
        for (int i = t; i < 64 * 8; i += 256) {
            const int row = i >> 3, ch = i & 7;
            const int sw = (ch * 16) ^ ((row & 7) << 4);
            *(short8*)((char*)As + row * 128 + sw) =
                *(const short8*)(A + (size_t)(r0 + row) * lda + kc + ch * 8);
        }
#pragma unroll
        for (int i = t; i < 128 * 8; i += 256) {
            const int row = i >> 3, ch = i & 7;
            const int sw = (ch * 16) ^ ((row & 7) << 4);
            *(short8*)((char*)Ws + row * 128 + sw) =
                *(const short8*)(Wt + (size_t)row * K + kc + ch * 8);
        }
        __syncthreads();
#pragma unroll
        for (int ks = 0; ks < 2; ++ks) {
            bf16x8 af[2], bfr[4];
#pragma unroll
            for (int m = 0; m < 2; ++m) {
                const int row = wm * 32 + m * 16 + lrow;
                const int col = (ks * 64 + lk * 16) ^ ((row & 7) << 4);
                af[m] = *(const bf16x8*)((const char*)As + row * 128 + col);
            }
#pragma unroll
            for (int n = 0; n < 4; ++n) {
                const int row = wn * 64 + n * 16 + lrow;
                const int col = (ks * 64 + lk * 16) ^ ((row & 7) << 4);
                bfr[n] = *(const bf16x8*)((const char*)Ws + row * 128 + col);
            }
#pragma unroll
            for (int m = 0; m < 2; ++m)
#pragma unroll
                for (int n = 0; n < 4; ++n)
                    acc[m][n] = __builtin_amdgcn_mfma_f32_16x16x32_bf16(
                        af[m], bfr[n], acc[m][n], 0, 0, 0);
        }
    }

    const int crow0 = (l >> 4) * 4;
    const int ccol = l & 15;
#pragma unroll
    for (int m = 0; m < 2; ++m) {
        const int growb = r0 + wm * 32 + m * 16 + crow0;
#pragma unroll
        for (int n = 0; n < 4; ++n) {
            const int gcol = wn * 64 + n * 16 + ccol;
            const float bv = bias[gcol];
#pragma unroll
            for (int j = 0; j < 4; ++j) {
                float v = acc[m][n][j] + bv;
                if (resid) v += bf2f(resid[(size_t)(growb + j) * 128 + gcol]);
                acc[m][n][j] = v;
            }
        }
    }
#pragma unroll
    for (int m = 0; m < 2; ++m)
#pragma unroll
        for (int j = 0; j < 4; ++j) {
            float s_ = 0.f, q_ = 0.f;
#pragma unroll
            for (int n = 0; n < 4; ++n) {
                const float x = acc[m][n][j];
                s_ += x; q_ += x * x;
            }
#pragma unroll
            for (int mk = 1; mk < 16; mk <<= 1) {
                s_ += __shfl_xor(s_, mk, 64);
                q_ += __shfl_xor(q_, mk, 64);
            }
            if (ccol == 0) {
                const int r = wm * 32 + m * 16 + crow0 + j;
                psum[r][wn][0] = s_;
                psum[r][wn][1] = q_;
            }
        }
    __syncthreads();   // psum ready; all K-loop reads of Ws complete
    float mean_[2][4], rstd_[2][4];
#pragma unroll
    for (int m = 0; m < 2; ++m)
#pragma unroll
        for (int j = 0; j < 4; ++j) {
            const int r = wm * 32 + m * 16 + crow0 + j;
            const float sum = psum[r][0][0] + psum[r][1][0];
            const float sq  = psum[r][0][1] + psum[r][1][1];
            const float mean = sum * 0.0078125f;
            const float var = sq * 0.0078125f - mean * mean;
            mean_[m][j] = mean;
            rstd_[m][j] = rsqrtf(var + 1e-5f);
        }
#pragma unroll
    for (int m = 0; m < 2; ++m) {
        const int growb = r0 + wm * 32 + m * 16 + crow0;
#pragma unroll
        for (int n = 0; n < 4; ++n) {
            const int gcol = wn * 64 + n * 16 + ccol;
            const float sv = lns[gcol], bv2 = lnbi[gcol];
#pragma unroll
            for (int j = 0; j < 4; ++j) {
                const float y = (acc[m][n][j] - mean_[m][j]) * rstd_[m][j] * sv + bv2;
                acc[m][n][j] = y;
                const size_t oi = (size_t)(growb + j) * 128 + gcol;
                if (Co) Co[oi] = y;
                if (Cb) Cb[oi] = f2bf(y);
            }
        }
    }

    if constexpr (FF || CKV) {
        // Restage y (bf16) into Ws reinterpreted as [64 rows][256 B], swizzled.
#pragma unroll
        for (int m = 0; m < 2; ++m) {
            const int rowb = wm * 32 + m * 16 + crow0;
#pragma unroll
            for (int n = 0; n < 4; ++n) {
                const int c = wn * 64 + n * 16 + ccol;
                const int cb = ((c >> 3) * 16);
#pragma unroll
                for (int j = 0; j < 4; ++j) {
                    const int row = rowb + j;
                    const int bo = row * 256 + ((cb) ^ ((row & 7) << 4)) + (c & 7) * 2;
                    *(ushort*)((char*)Ws + bo) = f2bf(acc[m][n][j]);
                }
            }
        }
    }

    if constexpr (FF) {
        for (int i = t; i < 1024; i += 256) {
            const int row = i >> 4, ch = i & 15;
            *(short8*)((char*)ffWs + row * 256 + ((ch * 16) ^ ((row & 7) << 4))) =
                *(const short8*)(ffW + (size_t)row * 128 + ch * 8);
        }
        __syncthreads();
        f32x4 accF[4];
#pragma unroll
        for (int n = 0; n < 4; ++n) accF[n] = (f32x4)0.f;
#pragma unroll
        for (int ks = 0; ks < 4; ++ks) {
            const int arow2 = w * 16 + lrow;
            const int acol = (ks * 64 + lk * 16) ^ ((arow2 & 7) << 4);
            const bf16x8 af = *(const bf16x8*)((const char*)Ws + arow2 * 256 + acol);
#pragma unroll
            for (int n = 0; n < 4; ++n) {
                const int brow = n * 16 + lrow;
                const int bcol = (ks * 64 + lk * 16) ^ ((brow & 7) << 4);
                const bf16x8 bf = *(const bf16x8*)((const char*)ffWs + brow * 256 + bcol);
                accF[n] = __builtin_amdgcn_mfma_f32_16x16x32_bf16(af, bf, accF[n], 0, 0, 0);
            }
        }
#pragma unroll
        for (int n = 0; n < 4; ++n) {
            const int gcol = n * 16 + ccol;
            const float bb = ffb[gcol];
#pragma unroll
            for (int j = 0; j < 4; ++j) {
                const int grow = r0 + w * 16 + crow0 + j;
                Fb[(size_t)grow * 64 + gcol] = f2bf(fmaxf(accF[n][j] + bb, 0.f));
            }
        }
    }

    if constexpr (CKV) {
        // 4 chunks of 64 output cols; out[64 rows][64 cols], K=128 per chunk.
        for (int cc = 0; cc < 4; ++cc) {
            __syncthreads();   // y visible (cc=0) / previous chunk reads done
            for (int i = t; i < 1024; i += 256) {
                const int row = i >> 4, ch = i & 15;
                *(short8*)((char*)ckvWs + row * 256 + ((ch * 16) ^ ((row & 7) << 4))) =
                    *(const short8*)(ckvW + (size_t)(cc * 64 + row) * 128 + ch * 8);
            }
            __syncthreads();
            f32x4 accC[4];
#pragma unroll
            for (int n = 0; n < 4; ++n) accC[n] = (f32x4)0.f;
#pragma unroll
            for (int ks = 0; ks < 4; ++ks) {
                const int arow2 = w * 16 + lrow;
                const int acol = (ks * 64 + lk * 16) ^ ((arow2 & 7) << 4);
                const bf16x8 af = *(const bf16x8*)((const char*)Ws + arow2 * 256 + acol);
#pragma unroll
                for (int n = 0; n < 4; ++n) {
                    const int brow = n * 16 + lrow;
                    const int bcol = (ks * 64 + lk * 16) ^ ((brow & 7) << 4);
                    const bf16x8 bf = *(const bf16x8*)((const char*)ckvWs + brow * 256 + bcol);
                    accC[n] = __builtin_amdgcn_mfma_f32_16x16x32_bf16(af, bf, accC[n], 0, 0, 0);
                }
            }
#pragma unroll
            for (int n = 0; n < 4; ++n) {
                const int gcol = cc * 64 + n * 16 + ccol;
                const float bb = ckvB[gcol];
#pragma unroll
                for (int j = 0; j < 4; ++j) {
                    const int grow = r0 + w * 16 + crow0 + j;
                    KVb[(size_t)grow * 256 + gcol] = f2bf(accC[n][j] + bb);
                }
            }
        }
    }
}

// ---------------------------------------------------------------------------
// MFMA flash attention, encoder self-attn (verified r3).
// ---------------------------------------------------------------------------
__global__ __launch_bounds__(256) void k_attn_mfma(
    const ushort* __restrict__ qkv, ushort* __restrict__ ob, float scale)
{
    __shared__ ushort Ks[208 * 40];
    __shared__ ushort Vt[32 * 232];
    __shared__ ushort Ps[4][16 * 232];
    const int bh = blockIdx.x;
    const int b = bh >> 2, h = bh & 3;
    const int t = threadIdx.x, w = t >> 6, l = t & 63;
    const int lr = l & 15, lg = l >> 4;

    for (int idx = t; idx < 784; idx += 256) {
        const int j = idx >> 2, ch = idx & 3;
        const size_t base = ((size_t)j * 256 + b) * 384 + h * 32 + ch * 8;
        *(short8*)(Ks + j * 40 + ch * 8) = *(const short8*)(qkv + base + 128);
        short8 v = *(const short8*)(qkv + base + 256);
#pragma unroll
        for (int q = 0; q < 8; ++q)
            Vt[(ch * 8 + q) * 232 + j] = (ushort)v[q];
    }
    for (int idx = t; idx < 32 * 36; idx += 256)
        Vt[(idx / 36) * 232 + 196 + (idx % 36)] = 0;
    for (int i = l; i < 256; i += 64)
        Ps[w][(i >> 4) * 232 + 208 + (i & 15)] = 0;
    __syncthreads();

    for (int qt = w; qt < 13; qt += 4) {
        int qr = qt * 16 + lr; if (qr > 195) qr = 195;
        const bf16x8 qf = *(const bf16x8*)(qkv + ((size_t)qr * 256 + b) * 384 + h * 32 + lg * 8);

        f32x4 s[13];
#pragma unroll
        for (int jn = 0; jn < 13; ++jn) {
            const bf16x8 kf = *(const bf16x8*)(Ks + (jn * 16 + lr) * 40 + lg * 8);
            s[jn] = __builtin_amdgcn_mfma_f32_16x16x32_bf16(qf, kf, (f32x4)0.f, 0, 0, 0);
        }
        if (lr >= 4) {
            s[12][0] = -3.0e38f; s[12][1] = -3.0e38f;
            s[12][2] = -3.0e38f; s[12][3] = -3.0e38f;
        }

        float inv[4];
        ushort* pw = Ps[w];
#pragma unroll
        for (int j = 0; j < 4; ++j) {
            float m = s[0][j];
#pragma unroll
            for (int jn = 1; jn < 13; ++jn) m = fmaxf(m, s[jn][j]);
            m = fmaxf(m, __shfl_xor(m, 1, 64));
            m = fmaxf(m, __shfl_xor(m, 2, 64));
            m = fmaxf(m, __shfl_xor(m, 4, 64));
            m = fmaxf(m, __shfl_xor(m, 8, 64));
            float sum = 0.f;
#pragma unroll
            for (int jn = 0; jn < 13; ++jn) {
                const float p = __expf((s[jn][j] - m) * scale);
                s[jn][j] = p;
                sum += p;
            }
            sum += __shfl_xor(sum, 1, 64);
            sum += __shfl_xor(sum, 2, 64);
            sum += __shfl_xor(sum, 4, 64);
            sum += __shfl_xor(sum, 8, 64);
            inv[j] = 1.0f / sum;
        }
#pragma unroll
        for (int jn = 0; jn < 13; ++jn)
#pragma unroll
            for (int j = 0; j < 4; ++j)
                pw[(lg * 4 + j) * 232 + jn * 16 + lr] = f2bf(s[jn][j]);

        f32x4 o0 = (f32x4)0.f, o1 = (f32x4)0.f;
#pragma unroll
        for (int kt = 0; kt < 7; ++kt) {
            const bf16x8 pf = *(const bf16x8*)(pw + lr * 232 + kt * 32 + lg * 8);
            const bf16x8 v0 = *(const bf16x8*)(Vt + lr * 232 + kt * 32 + lg * 8);
            const bf16x8 v1 = *(const bf16x8*)(Vt + (16 + lr) * 232 + kt * 32 + lg * 8);
            o0 = __builtin_amdgcn_mfma_f32_16x16x32_bf16(pf, v0, o0, 0, 0, 0);
            o1 = __builtin_amdgcn_mfma_f32_16x16x32_bf16(pf, v1, o1, 0, 0, 0);
        }
#pragma unroll
        for (int j = 0; j < 4; ++j) {
            const int r = qt * 16 + lg * 4 + j;
            if (r < 196) {
                const size_t o = ((size_t)r * 256 + b) * 128 + h * 32;
                ob[o + lr]      = f2bf(o0[j] * inv[j]);
                ob[o + 16 + lr] = f2bf(o1[j] * inv[j]);
            }
        }
    }
}

// ---------------------------------------------------------------------------
// Fused attention (decoder cross path; f32 math, KV stored bf16, verified r22).
// ---------------------------------------------------------------------------
__global__ __launch_bounds__(256) void k_attn(
    const float* __restrict__ qp, int qstride,
    const ushort* __restrict__ kvp, int kvstride, int koff, int voff,
    float* __restrict__ op, ushort* __restrict__ ob,
    int Lq, int Lk, float scale)
{
    __shared__ float Kl[196 * 36];
    __shared__ float Vl[196 * 32];
    __shared__ float pbuf[4][256];
    const int bh = blockIdx.x;
    const int b = bh >> 2;
    const int h = bh & 3;
    const int t = threadIdx.x;
    const int w = t >> 6;
    const int l = t & 63;

    for (int idx = t; idx < Lk * 8; idx += 256) {
        const int j = idx >> 3;
        const int kq = idx & 7;
        const size_t row = ((size_t)j * 256 + b) * kvstride + h * 32 + kq * 4;
        const ushort4 k4 = *(const ushort4*)(kvp + row + koff);
        const ushort4 v4 = *(const ushort4*)(kvp + row + voff);
        Kl[j * 36 + kq * 4 + 0] = bf2f(k4.x);
        Kl[j * 36 + kq * 4 + 1] = bf2f(k4.y);
        Kl[j * 36 + kq * 4 + 2] = bf2f(k4.z);
        Kl[j * 36 + kq * 4 + 3] = bf2f(k4.w);
        Vl[j * 32 + kq * 4 + 0] = bf2f(v4.x);
        Vl[j * 32 + kq * 4 + 1] = bf2f(v4.y);
        Vl[j * 32 + kq * 4 + 2] = bf2f(v4.z);
        Vl[j * 32 + kq * 4 + 3] = bf2f(v4.w);
    }
    if ((Lk & 1) && t < 8) *(float4*)(&Vl[Lk * 32 + t * 4]) = make_float4(0.f, 0.f, 0.f, 0.f);
    __syncthreads();

    const int Lh = (Lk + 1) >> 1;
    const int half = l >> 5;
    const int kk = l & 31;
    const int jb = half * Lh;

    for (int jq = w; jq < Lq; jq += 4) {
        const float* qrow = qp + ((size_t)jq * 256 + b) * qstride + h * 32;
        float4 q4[8];
#pragma unroll
        for (int kq = 0; kq < 8; ++kq) q4[kq] = *(const float4*)(qrow + kq * 4);

        float s[4];
#pragma unroll
        for (int r = 0; r < 4; ++r) {
            const int j = l + (r << 6);
            float acc = -3.0e38f;
            if (j < Lk) {
                acc = 0.f;
#pragma unroll
                for (int kq = 0; kq < 8; ++kq) {
                    const float4 kv = *(const float4*)(&Kl[j * 36 + kq * 4]);
                    acc += q4[kq].x * kv.x + q4[kq].y * kv.y +
                           q4[kq].z * kv.z + q4[kq].w * kv.w;
                }
                acc *= scale;
            }
            s[r] = acc;
        }
        float m = fmaxf(fmaxf(s[0], s[1]), fmaxf(s[2], s[3]));
        m = wred_max(m);
        float sum = 0.f;
#pragma unroll
        for (int r = 0; r < 4; ++r) {
            const int j = l + (r << 6);
            float p = __expf(s[r] - m);
            if (j >= Lk) p = 0.f;
            pbuf[w][j] = p;
            sum += p;
        }
        sum = wred_sum(sum);
        const float inv = 1.0f / sum;
        __threadfence_block();

        float o = 0.f;
        for (int jj = 0; jj < Lh; ++jj) {
            const float pv = pbuf[w][jb + jj];
            const float vv = Vl[(jb + jj) * 32 + kk];
            o += pv * vv;
        }
        o += __shfl_xor(o, 32, 64);
        o *= inv;
        if (l < 32) {
            const size_t oi = ((size_t)jq * 256 + b) * 128 + h * 32 + l;
            if (op) op[oi] = o;
            if (ob) ob[oi] = f2bf(o);
        }
        __threadfence_block();
    }
}

// ---------------------------------------------------------------------------
// Fused decoder part 2 v3 (verified r9) + L2 weight prefetch (r17).
// ---------------------------------------------------------------------------
__global__ __launch_bounds__(512) void k_dec2(
    const float* __restrict__ TGo, const float* __restrict__ AT,
    const float* __restrict__ caoW, const float* __restrict__ caob,
    const float* __restrict__ ln2s, const float* __restrict__ ln2b,
    const float* __restrict__ ff1W, const float* __restrict__ ff1b,
    const float* __restrict__ ff2W, const float* __restrict__ ff2b,
    const float* __restrict__ ln3s, const float* __restrict__ ln3b,
    const float* __restrict__ ns, const float* __restrict__ nb,
    const float* __restrict__ l1W, const float* __restrict__ l1b,
    const float* __restrict__ l2w, const float* __restrict__ l2b,
    float* __restrict__ qout)
{
    __shared__ float tg[15][128], ao[15][128], o2[15][128];
    __shared__ float ff[15][64];
    const int b = blockIdx.x, t = threadIdx.x;
    const int w = t >> 6, l = t & 63;

    {
        float pf = 0.f;
#define PFW(P, N) for (int i = t * 32; i < (N); i += 512 * 32) pf += P[i];
        PFW(caoW, 128 * 128)
        PFW(ff1W, 128 * 64)
        PFW(ff2W, 64 * 128)
        PFW(l1W, 128 * 128)
#undef PFW
        asm volatile("" :: "v"(pf));
    }

    for (int idx = t; idx < 1920; idx += 512) {
        const int r = idx >> 7, c = idx & 127;
        tg[r][c] = TGo[((size_t)r * 256 + b) * 128 + c];
        ao[r][c] = AT[((size_t)r * 256 + b) * 128 + c];
    }
    __syncthreads();

    {
        const int c = t & 127, g = t >> 7;
        const int r3 = (g + 12 < 15) ? g + 12 : 0;
        float a0 = 0.f, a1 = 0.f, a2 = 0.f, a3 = 0.f;
#pragma unroll 4
        for (int k = 0; k < 128; ++k) {
            const float wv = caoW[(size_t)k * 128 + c];
            a0 += ao[g][k] * wv;
            a1 += ao[g + 4][k] * wv;
            a2 += ao[g + 8][k] * wv;
            a3 += ao[r3][k] * wv;
        }
        const float bb = caob[c];
        o2[g][c]     = a0 + bb + tg[g][c];
        o2[g + 4][c] = a1 + bb + tg[g + 4][c];
        o2[g + 8][c] = a2 + bb + tg[g + 8][c];
        if (g + 12 < 15) o2[g + 12][c] = a3 + bb + tg[g + 12][c];
    }
    __syncthreads();
    for (int r = w; r < 15; r += 8) {
        const float x0 = o2[r][l], x1 = o2[r][l + 64];
        const float sm = wred_sum(x0 + x1);
        const float sq = wred_sum(x0 * x0 + x1 * x1);
        const float mean = sm * 0.0078125f;
        const float rstd = rsqrtf(sq * 0.0078125f - mean * mean + 1e-5f);
        tg[r][l]      = (x0 - mean) * rstd * ln2s[l] + ln2b[l];
        tg[r][l + 64] = (x1 - mean) * rstd * ln2s[l + 64] + ln2b[l + 64];
    }
    __syncthreads();
    {
        const int n = t & 63, g = t >> 6;
        const int r1 = (g + 8 < 15) ? g + 8 : 0;
        float a0 = 0.f, a1 = 0.f;
#pragma unroll 4
        for (int k = 0; k < 128; ++k) {
            const float wv = ff1W[(size_t)k * 64 + n];
            a0 += tg[g][k] * wv;
            a1 += tg[r1][k] * wv;
        }
        const float bb = ff1b[n];
        ff[g][n] = fmaxf(a0 + bb, 0.f);
        if (g + 8 < 15) ff[g + 8][n] = fmaxf(a1 + bb, 0.f);
    }
    __syncthreads();
    {
        const int c = t & 127, g = t >> 7;
        const int r3 = (g + 12 < 15) ? g + 12 : 0;
        float a0 = 0.f, a1 = 0.f, a2 = 0.f, a3 = 0.f;
#pragma unroll 4
        for (int k = 0; k < 64; ++k) {
            const float wv = ff2W[(size_t)k * 128 + c];
            a0 += ff[g][k] * wv;
            a1 += ff[g + 4][k] * wv;
            a2 += ff[g + 8][k] * wv;
            a3 += ff[r3][k] * wv;
        }
        const float bb = ff2b[c];
        o2[g][c]     = a0 + bb + tg[g][c];
        o2[g + 4][c] = a1 + bb + tg[g + 4][c];
        o2[g + 8][c] = a2 + bb + tg[g + 8][c];
        if (g + 12 < 15) o2[g + 12][c] = a3 + bb + tg[g + 12][c];
    }
    __syncthreads();
    for (int r = w; r < 15; r += 8) {
        const float x0 = o2[r][l], x1 = o2[r][l + 64];
        const float sm = wred_sum(x0 + x1);
        const float sq = wred_sum(x0 * x0 + x1 * x1);
        const float mean = sm * 0.0078125f;
        const float rstd = rsqrtf(sq * 0.0078125f - mean * mean + 1e-5f);
        const float y0 = (x0 - mean) * rstd * ln3s[l] + ln3b[l];
        const float y1 = (x1 - mean) * rstd * ln3s[l + 64] + ln3b[l + 64];
        const float sm2 = wred_sum(y0 + y1);
        const float sq2 = wred_sum(y0 * y0 + y1 * y1);
        const float mean2 = sm2 * 0.0078125f;
        const float rstd2 = rsqrtf(sq2 * 0.0078125f - mean2 * mean2 + 1e-5f);
        tg[r][l]      = (y0 - mean2) * rstd2 * ns[l] + nb[l];
        tg[r][l + 64] = (y1 - mean2) * rstd2 * ns[l + 64] + nb[l + 64];
    }
    __syncthreads();
    {
        const int c = t & 127, g = t >> 7;
        const int r3 = (g + 12 < 15) ? g + 12 : 0;
        float a0 = 0.f, a1 = 0.f, a2 = 0.f, a3 = 0.f;
#pragma unroll 4
        for (int k = 0; k < 128; ++k) {
            const float wv = l1W[(size_t)k * 128 + c];
            a0 += tg[g][k] * wv;
            a1 += tg[g + 4][k] * wv;
            a2 += tg[g + 8][k] * wv;
            a3 += tg[r3][k] * wv;
        }
        const float bb = l1b[c];
        o2[g][c]     = fmaxf(a0 + bb, 0.f);
        o2[g + 4][c] = fmaxf(a1 + bb, 0.f);
        o2[g + 8][c] = fmaxf(a2 + bb, 0.f);
        if (g + 12 < 15) o2[g + 12][c] = fmaxf(a3 + bb, 0.f);
    }
    __syncthreads();
    for (int r = w; r < 15; r += 8) {
        const float d = wred_sum(o2[r][l] * l2w[l] + o2[r][l + 64] * l2w[l + 64]);
        if (l == 0) qout[b * 15 + r] = d + l2b[0];
    }
}

// ---------------------------------------------------------------------------
extern "C" void kernel_launch(void* const* d_in, const int* in_sizes, int n_in,
                              void* d_out, int out_size, void* d_ws, size_t ws_size,
                              hipStream_t stream)
{
    (void)in_sizes; (void)n_in; (void)out_size; (void)ws_size;
    const float* image      = (const float*)d_in[0];
    const float* angle      = (const float*)d_in[1];
    const float* pos_x      = (const float*)d_in[2];
    const float* pos_y      = (const float*)d_in[3];
    const float* sk         = (const float*)d_in[4];
    const float* patch_W    = (const float*)d_in[5];
    const float* patch_b    = (const float*)d_in[6];
    const float* pos_emb    = (const float*)d_in[7];
    const float* enc_qkv_W  = (const float*)d_in[8];
    const float* enc_qkv_b  = (const float*)d_in[9];
    const float* enc_out_W  = (const float*)d_in[10];
    const float* enc_out_b  = (const float*)d_in[11];
    const float* enc_ln1_s  = (const float*)d_in[12];
    const float* enc_ln1_b  = (const float*)d_in[13];
    const float* enc_ff1_W  = (const float*)d_in[14];
    const float* enc_ff1_b  = (const float*)d_in[15];
    const float* enc_ff2_W  = (const float*)d_in[16];
    const float* enc_ff2_b  = (const float*)d_in[17];
    const float* enc_ln2_s  = (const float*)d_in[18];
    const float* enc_ln2_b  = (const float*)d_in[19];
    const float* dec_sa_qkv_W = (const float*)d_in[20];
    const float* dec_sa_qkv_b = (const float*)d_in[21];
    const float* dec_sa_out_W = (const float*)d_in[22];
    const float* dec_sa_out_b = (const float*)d_in[23];
    const float* dec_ca_qkv_W = (const float*)d_in[24];
    const float* dec_ca_qkv_b = (const float*)d_in[25];
    const float* dec_ca_out_W = (const float*)d_in[26];
    const float* dec_ca_out_b = (const float*)d_in[27];
    const float* dec_ln1_s  = (const float*)d_in[28];
    const float* dec_ln1_b  = (const float*)d_in[29];
    const float* dec_ln2_s  = (const float*)d_in[30];
    const float* dec_ln2_b  = (const float*)d_in[31];
    const float* dec_ln3_s  = (const float*)d_in[32];
    const float* dec_ln3_b  = (const float*)d_in[33];
    const float* dec_ff1_W  = (const float*)d_in[34];
    const float* dec_ff1_b  = (const float*)d_in[35];
    const float* dec_ff2_W  = (const float*)d_in[36];
    const float* dec_ff2_b  = (const float*)d_in[37];
    const float* dec_norm_s = (const float*)d_in[38];
    const float* dec_norm_b = (const float*)d_in[39];
    const float* sk1_W = (const float*)d_in[40];
    const float* sk1_b = (const float*)d_in[41];
    const float* sk2_W = (const float*)d_in[42];
    const float* sk2_b = (const float*)d_in[43];
    const float* sk3_W = (const float*)d_in[44];
    const float* sk3_b = (const float*)d_in[45];
    const float* act_W = (const float*)d_in[46];
    const float* act_b = (const float*)d_in[47];
    const float* l1_W  = (const float*)d_in[48];
    const float* l1_b  = (const float*)d_in[49];
    const float* l2_W  = (const float*)d_in[50];
    const float* l2_b  = (const float*)d_in[51];

    // Workspace (float offsets)
    float* ws = (float*)d_ws;
    float* S0   = ws;               // src bf16 residual stream (home region)
    float* QKVr = ws + 6422528;     // big overlay region       [19,267,584]
    float* T0   = ws + 25690112;    // decoder cross-attn out   [6,422,528]
    float* T1   = ws + 32112640;    // LN1-out bf16 home        [6,422,528]
    float* F1   = ws + 38535168;    // F1b bf16                 [3,211,264]
    float* M0r  = ws + 41746432;    // T0b bf16                 [6,422,528]
    float* S1s  = ws + 48168960;
    float* TG   = S1s + 156672;     // tgt f32 15*256*128
    ushort* WTS = (ushort*)(ws + 48817152);

    // Overlays
    ushort* QKVb = (ushort*)QKVr;            // enc QKV bf16 [50176][384]
    ushort* KVb  = (ushort*)QKVr;            // cross K/V bf16 [50176][256] (disjoint lifetime)
    float* DQ   = QKVr + 14319616;           // dec cross Q f32
    float* DT0  = T0;
    ushort* S0b  = (ushort*)S0;              // src residual bf16 [50176][128]
    ushort* S1b  = (ushort*)T1;              // LN1-out residual bf16 [50176][128]
    ushort* T0b  = (ushort*)M0r;
    ushort* F1b  = (ushort*)F1;
    ushort* wt_patch = WTS;
    ushort* wt_qkv   = WTS + 98304;
    ushort* wt_out   = WTS + 147456;
    ushort* wt_ff1   = WTS + 163840;
    ushort* wt_ff2   = WTS + 172032;
    ushort* wt_ckv   = WTS + 180224;

    const float rs = 0.17677669529663687f;  // 1/sqrt(32)

    // ---- prep ----
    k_wconv<<<dim3(832), 256, 0, stream>>>(patch_W, enc_qkv_W, enc_out_W,
                                           enc_ff1_W, enc_ff2_W, dec_ca_qkv_W, WTS);

    // ---- merged dec1 + patchify-GEMM + fused QKV (src residual bf16) ----
    k_pg_dec1<<<dim3(1040), 512, 49152, stream>>>(
        image, wt_patch, patch_b, pos_emb, S0b,
        wt_qkv, enc_qkv_b, QKVb,
        sk, sk1_W, sk1_b, sk2_W, sk2_b, sk3_W, sk3_b,
        angle, pos_x, pos_y, act_W, act_b,
        dec_sa_qkv_W, dec_sa_qkv_b, dec_sa_out_W, dec_sa_out_b,
        dec_ln1_s, dec_ln1_b, dec_ca_qkv_W, dec_ca_qkv_b, TG, DQ);

    // ---- encoder ----
    k_attn_mfma<<<dim3(1024), 256, 0, stream>>>(QKVb, T0b, rs);
    k_gemm_ln<1, 0><<<dim3(784), 256, 0, stream>>>(           // out-proj + LN1 + FF1
        T0b, 128, wt_out, 128, enc_out_b, S0b, enc_ln1_s, enc_ln1_b,
        nullptr, S1b, wt_ff1, enc_ff1_b, F1b, nullptr, nullptr, nullptr);
    k_gemm_ln<0, 1><<<dim3(784), 256, 0, stream>>>(           // FF2 + LN2 + cross-KV(bf16)
        F1b, 64, wt_ff2, 64, enc_ff2_b, S1b, enc_ln2_s, enc_ln2_b,
        nullptr, nullptr, nullptr, nullptr, nullptr,
        wt_ckv, dec_ca_qkv_b + 128, KVb);

    // ---- decoder cross-attn + tail ----
    k_attn<<<dim3(1024), 256, 0, stream>>>(DQ, 128, KVb, 256, 0, 128,
                                           DT0, nullptr, 15, 196, rs);
    k_dec2<<<dim3(256), 512, 0, stream>>>(
        TG, DT0, dec_ca_out_W, dec_ca_out_b, dec_ln2_s, dec_ln2_b,
        dec_ff1_W, dec_ff1_b, dec_ff2_W, dec_ff2_b,
        dec_ln3_s, dec_ln3_b, dec_norm_s, dec_norm_b,
        l1_W, l1_b, l2_W, l2_b, (float*)d_out);
}